// Round 3
// baseline (551.225 us; speedup 1.0000x reference)
//
#include <hip/hip_runtime.h>
#include <hip/hip_bf16.h>
#include <math.h>
#include <stdint.h>

// Problem constants (fixed by reference)
#define NATOMS 4096
#define HD     128
#define NHEAD  4
#define DHEAD  32
#define FDIM   259
#define BATCH  128
#define H3X    384   // 3*H

// block reduction for 128 threads (2 waves)
__device__ __forceinline__ float blk_sum_128(float v, float* scratch) {
#pragma unroll
    for (int o = 32; o; o >>= 1) v += __shfl_down(v, o);
    int lane = threadIdx.x & 63, w = threadIdx.x >> 6;
    if (lane == 0) scratch[w] = v;
    __syncthreads();
    float r = scratch[0] + scratch[1];
    __syncthreads();
    return r;
}

// ---------------- prep: bidx (exact repeat semantics), per-row clamp bounds ----
__global__ void k_prep(const int* __restrict__ num_atoms, const float* __restrict__ cell,
                       int* __restrict__ bidx, float* __restrict__ cmin, float* __restrict__ cmax) {
    __shared__ int start[BATCH + 1];
    int t = threadIdx.x;  // 128 threads
    if (t == 0) {
        int pos = 0;
        for (int b = 0; b < BATCH; b++) { start[b] = pos; pos += num_atoms[b]; }
        start[BATCH] = pos;
    }
    __syncthreads();
    int s = min(start[t], NATOMS), e = min(start[t + 1], NATOMS);
    for (int j = s; j < e; j++) bidx[j] = t;
    if (t == 0) {
        int total = min(start[BATCH], NATOMS);
        for (int j = total; j < NATOMS; j++) bidx[j] = BATCH - 1;  // repeat pads with last value
    }
    // cmin/cmax: c3=cell.reshape(B,3,3); cmin[b][i]=min_j c3[b][i][j]+1e-6
    for (int rr = t; rr < BATCH * 3; rr += blockDim.x) {
        float a0 = cell[rr * 3 + 0], a1 = cell[rr * 3 + 1], a2 = cell[rr * 3 + 2];
        cmin[rr] = fminf(a0, fminf(a1, a2)) + 1e-6f;
        cmax[rr] = fmaxf(a0, fmaxf(a1, a2)) - 1e-6f;
    }
}

// ---------------- embedding gather + input LayerNorm -> X [N,128] fp32 --------
__global__ void k_embed_ln(const int* __restrict__ elems, const float* __restrict__ emb,
                           const float* __restrict__ g, const float* __restrict__ b,
                           float* __restrict__ X) {
    __shared__ float sc[2];
    int row = blockIdx.x, t = threadIdx.x;
    int e = elems[row];
    float v = emb[e * HD + t];
    float mean = blk_sum_128(v, sc) * (1.f / HD);
    float d = v - mean;
    float var = blk_sum_128(d * d, sc) * (1.f / HD);
    X[row * HD + t] = d * rsqrtf(var + 1e-5f) * g[t] + b[t];
}

// ---------------- generic LN over width 128, in-place, optional silu ----------
__global__ void k_ln128(float* __restrict__ buf, const float* __restrict__ g,
                        const float* __restrict__ b, int silu) {
    __shared__ float sc[2];
    int row = blockIdx.x, t = threadIdx.x;
    float v = buf[row * HD + t];
    float mean = blk_sum_128(v, sc) * (1.f / HD);
    float d = v - mean;
    float var = blk_sum_128(d * d, sc) * (1.f / HD);
    float o = d * rsqrtf(var + 1e-5f) * g[t] + b[t];
    if (silu) o = o / (1.f + __expf(-o));
    buf[row * HD + t] = o;
}

// ---------------- generic row-block GEMM: C[M,N] = A[M,K]fp32 @ W[K,N]fp32 + bias
// block = N/2 threads, each thread owns 2 adjacent columns (float2 weight load)
template <int KDIM, int NDIM>
__global__ void k_gemm(const float* __restrict__ A, const float* __restrict__ W,
                       const float* __restrict__ bias, const float* __restrict__ resid,
                       float* __restrict__ C, int silu) {
    __shared__ float a_s[KDIM];
    int row = blockIdx.x, t = threadIdx.x;
    for (int k = t; k < KDIM; k += blockDim.x) a_s[k] = A[row * KDIM + k];
    __syncthreads();
    int j = t * 2;
    if (j < NDIM) {
        float acc0 = bias[j], acc1 = bias[j + 1];
        const float2* Wp = reinterpret_cast<const float2*>(W);
#pragma unroll 4
        for (int k = 0; k < KDIM; k++) {
            float2 w = Wp[(k * NDIM + j) >> 1];
            float a = a_s[k];
            acc0 += a * w.x;
            acc1 += a * w.y;
        }
        if (resid) { acc0 += resid[row * NDIM + j]; acc1 += resid[row * NDIM + j + 1]; }
        if (silu) {
            acc0 = acc0 / (1.f + __expf(-acc0));
            acc1 = acc1 / (1.f + __expf(-acc1));
        }
        C[row * NDIM + j] = acc0;
        C[row * NDIM + j + 1] = acc1;
    }
}

// ---------------- cell encoder: cf[r] = silu(cell[r]@w1+b1)@w2+b2, rows 0..127 --
__global__ void k_cell(const float* __restrict__ cell, const float* __restrict__ w1,
                       const float* __restrict__ b1, const float* __restrict__ w2,
                       const float* __restrict__ b2, float* __restrict__ CF) {
    __shared__ float hs[HD];
    int r = blockIdx.x, t = threadIdx.x;
    float c0 = cell[r * 3 + 0], c1 = cell[r * 3 + 1], c2 = cell[r * 3 + 2];
    float h = c0 * w1[0 * HD + t] + c1 * w1[1 * HD + t] + c2 * w1[2 * HD + t] + b1[t];
    h = h / (1.f + __expf(-h));
    hs[t] = h;
    __syncthreads();
    float acc = b2[t];
#pragma unroll 8
    for (int k = 0; k < HD; k++) acc += hs[k] * w2[k * HD + t];
    CF[r * HD + t] = acc;
}

// ---------------- attention: flash-style, TQ=8 queries/block, TK=64 key tile ---
// scores use constant max-shift (scores provably bounded |s| << 12 for this
// model's scales; softmax ratios are exact under a common exp scale in fp32).
#define TQ 8
#define TK 64
#define MSHIFT 12.0f
__global__ __launch_bounds__(256) void k_attn(const float* __restrict__ QKV, float* __restrict__ ATT) {
    __shared__ float K_s[TK][33];
    __shared__ float V_s[TK][33];
    __shared__ float P_s[TQ][TK];
    __shared__ float qv_s[TQ * DHEAD];
    __shared__ float lsum[TQ];

    int t = threadIdx.x;                // 256 threads
    int hh = blockIdx.y;                // head
    int q0 = blockIdx.x * TQ;           // first query of tile

    // load Q tile (scaled by 1/sqrt(DH)) into LDS, then per-thread registers
    {
        int qi = t >> 5, d = t & 31;    // 8*32 == 256
        qv_s[t] = QKV[(q0 + qi) * H3X + hh * DHEAD + d] * 0.17677669529663687f;
    }
    __syncthreads();
    int g = t >> 6;                      // wave id 0..3 -> query pair (2g, 2g+1)
    int kk = t & 63;                     // key-in-tile for score phase
    float q0r[32], q1r[32];
#pragma unroll
    for (int j = 0; j < 32; j++) {
        q0r[j] = qv_s[(g * 2) * 32 + j];
        q1r[j] = qv_s[(g * 2 + 1) * 32 + j];
    }

    float lacc0 = 0.f, lacc1 = 0.f;      // softmax denominators (partial)
    float acc[TQ];                       // PV accumulators: thread owns (d=t&31, chunk c=t>>5)
#pragma unroll
    for (int qi = 0; qi < TQ; qi++) acc[qi] = 0.f;

    for (int kt = 0; kt < NATOMS; kt += TK) {
        __syncthreads();  // protect LDS reuse across tiles
        // stage K,V tiles: 64 rows x 32 cols each; 512 float4 per matrix / 256 thr
#pragma unroll
        for (int jj = 0; jj < 2; jj++) {
            int i4 = t + 256 * jj;
            int r = i4 >> 3, c4 = (i4 & 7) * 4;
            const float* kp = &QKV[(kt + r) * H3X + HD + hh * DHEAD + c4];
            float4 kv = *reinterpret_cast<const float4*>(kp);
            K_s[r][c4 + 0] = kv.x; K_s[r][c4 + 1] = kv.y; K_s[r][c4 + 2] = kv.z; K_s[r][c4 + 3] = kv.w;
            const float* vp = &QKV[(kt + r) * H3X + 2 * HD + hh * DHEAD + c4];
            float4 vv = *reinterpret_cast<const float4*>(vp);
            V_s[r][c4 + 0] = vv.x; V_s[r][c4 + 1] = vv.y; V_s[r][c4 + 2] = vv.z; V_s[r][c4 + 3] = vv.w;
        }
        __syncthreads();
        // score phase: this thread computes scores (2 queries) for key kk
        float s0 = 0.f, s1 = 0.f;
#pragma unroll
        for (int j = 0; j < 32; j++) {
            float kv = K_s[kk][j];
            s0 += q0r[j] * kv;
            s1 += q1r[j] * kv;
        }
        float p0 = __expf(s0 - MSHIFT), p1 = __expf(s1 - MSHIFT);
        lacc0 += p0; lacc1 += p1;
        P_s[g * 2][kk] = p0;
        P_s[g * 2 + 1][kk] = p1;
        __syncthreads();
        // PV phase: thread (d=t&31, chunk c=t>>5) accumulates 8 keys for all 8 queries
        int d = t & 31, c = t >> 5;
#pragma unroll
        for (int k8 = 0; k8 < 8; k8++) {
            int k2 = c * 8 + k8;
            float vv = V_s[k2][d];
#pragma unroll
            for (int qi = 0; qi < TQ; qi++) acc[qi] += P_s[qi][k2] * vv;
        }
    }

    // reduce softmax denominators: threads of wave g all handled queries 2g,2g+1
#pragma unroll
    for (int o = 32; o; o >>= 1) { lacc0 += __shfl_down(lacc0, o); lacc1 += __shfl_down(lacc1, o); }
    if ((t & 63) == 0) { lsum[g * 2] = lacc0; lsum[g * 2 + 1] = lacc1; }
    // reduce PV partials across 8 chunks via LDS (overlay on K_s: 2048 <= 2112 floats)
    float* red = &K_s[0][0];
    {
        int d = t & 31, c = t >> 5;
#pragma unroll
        for (int qi = 0; qi < TQ; qi++) red[qi * 256 + c * 32 + d] = acc[qi];
    }
    __syncthreads();
    {
        int qi = t >> 5, d = t & 31;   // 8*32 == 256
        float o = 0.f;
#pragma unroll
        for (int c = 0; c < 8; c++) o += red[qi * 256 + c * 32 + d];
        ATT[(q0 + qi) * HD + hh * DHEAD + d] = o / lsum[qi];
    }
}

// ---------------- concat [x1 | cf[bidx] | coord] + LN over F=259 ---------------
__global__ void k_comb(const float* __restrict__ X1, const float* __restrict__ CF,
                       const float* __restrict__ coord, const int* __restrict__ bidx,
                       const float* __restrict__ g, const float* __restrict__ b,
                       float* __restrict__ COMB) {
    __shared__ float sc[2];
    int row = blockIdx.x, t = threadIdx.x;
    int bi = bidx[row];
    float v0 = X1[row * HD + t];
    float v1 = CF[bi * HD + t];
    float v2 = (t < 3) ? coord[row * 3 + t] : 0.f;
    float tot = blk_sum_128(v0 + v1 + v2, sc);
    float mean = tot * (1.f / FDIM);
    float d0 = v0 - mean, d1 = v1 - mean, d2 = (t < 3) ? (v2 - mean) : 0.f;
    float var = blk_sum_128(d0 * d0 + d1 * d1 + d2 * d2, sc) * (1.f / FDIM);
    float inv = rsqrtf(var + 1e-5f);
    COMB[row * FDIM + t] = d0 * inv * g[t] + b[t];
    COMB[row * FDIM + 128 + t] = d1 * inv * g[128 + t] + b[128 + t];
    if (t < 3) COMB[row * FDIM + 256 + t] = d2 * inv * g[256 + t] + b[256 + t];
}

// ---------------- final: offset = tanh(h@w3+b3)*0.01; clip(coord+offset) -------
// OUTPUT IS FLOAT32 (reference returns float32; harness reads np.float32).
__global__ void k_out(const float* __restrict__ Hf, const float* __restrict__ w3,
                      const float* __restrict__ b3, const float* __restrict__ coord,
                      const int* __restrict__ bidx, const float* __restrict__ cmin,
                      const float* __restrict__ cmax, float* __restrict__ out) {
    __shared__ float sc[2];
    __shared__ float offs[3];
    int row = blockIdx.x, t = threadIdx.x;
    float hv = Hf[row * HD + t];
    for (int c = 0; c < 3; c++) {
        float tot = blk_sum_128(hv * w3[t * 3 + c], sc);
        if (t == 0) offs[c] = tanhf(tot + b3[c]) * 0.01f;
    }
    __syncthreads();
    if (t < 3) {
        int bi = bidx[row];
        float pert = coord[row * 3 + t] + offs[t];
        pert = fminf(fmaxf(pert, cmin[bi * 3 + t]), cmax[bi * 3 + t]);
        out[row * 3 + t] = pert;
    }
}

extern "C" void kernel_launch(void* const* d_in, const int* in_sizes, int n_in,
                              void* d_out, int out_size, void* d_ws, size_t ws_size,
                              hipStream_t stream) {
    const int* num_atoms = (const int*)d_in[0];
    const int* elems = (const int*)d_in[1];
    const float* cell = (const float*)d_in[2];
    const float* coord = (const float*)d_in[3];
    const float* emb = (const float*)d_in[4];
    const float* ln_in_g = (const float*)d_in[5];
    const float* ln_in_b = (const float*)d_in[6];
    const float* attn_in_w = (const float*)d_in[7];
    const float* attn_in_b = (const float*)d_in[8];
    const float* attn_out_w = (const float*)d_in[9];
    const float* attn_out_b = (const float*)d_in[10];
    const float* ce_w1 = (const float*)d_in[11];
    const float* ce_b1 = (const float*)d_in[12];
    const float* ce_w2 = (const float*)d_in[13];
    const float* ce_b2 = (const float*)d_in[14];
    const float* ln_feat_g = (const float*)d_in[15];
    const float* ln_feat_b = (const float*)d_in[16];
    const float* op_w1 = (const float*)d_in[17];
    const float* op_b1 = (const float*)d_in[18];
    const float* op_ln1_g = (const float*)d_in[19];
    const float* op_ln1_b = (const float*)d_in[20];
    const float* res_w1 = (const float*)d_in[21];
    const float* res_b1 = (const float*)d_in[22];
    const float* res_ln_g = (const float*)d_in[23];
    const float* res_ln_b = (const float*)d_in[24];
    const float* res_w2 = (const float*)d_in[25];
    const float* res_b2 = (const float*)d_in[26];
    const float* op_ln2_g = (const float*)d_in[27];
    const float* op_ln2_b = (const float*)d_in[28];
    const float* op_w3 = (const float*)d_in[29];
    const float* op_b3 = (const float*)d_in[30];

    // workspace layout (~12.1 MB total, all fp32, lifetimes tracked for reuse):
    char* ws = (char*)d_ws;
    float* X = (float*)(ws + 0);                    // slot0 2MB: X, later ATT
    float* QKV = (float*)(ws + (2u << 20));         // slot1 6MB: QKV -> COMB -> R
    float* ATT = X;
    float* X1 = (float*)(ws + (8u << 20));          // slot2 2MB: X1 -> H2
    float* COMB = QKV;
    float* Hb = (float*)(ws + (10u << 20));         // slot3 2MB: H
    float* Rb = QKV;
    float* H2 = X1;
    int* bidx = (int*)(ws + (12u << 20));           // 16KB
    float* cmin = (float*)(ws + (12u << 20) + 16384);
    float* cmax = cmin + BATCH * 3;
    float* CF = (float*)(ws + (12u << 20) + 20480); // 64KB

    k_prep<<<1, 128, 0, stream>>>(num_atoms, cell, bidx, cmin, cmax);
    k_embed_ln<<<NATOMS, 128, 0, stream>>>(elems, emb, ln_in_g, ln_in_b, X);
    k_gemm<128, 384><<<NATOMS, 192, 0, stream>>>(X, attn_in_w, attn_in_b, nullptr, QKV, 0);
    k_attn<<<dim3(NATOMS / TQ, NHEAD), 256, 0, stream>>>(QKV, ATT);
    k_gemm<128, 128><<<NATOMS, 64, 0, stream>>>(ATT, attn_out_w, attn_out_b, nullptr, X1, 0);
    k_cell<<<BATCH, 128, 0, stream>>>(cell, ce_w1, ce_b1, ce_w2, ce_b2, CF);
    k_comb<<<NATOMS, 128, 0, stream>>>(X1, CF, coord, bidx, ln_feat_g, ln_feat_b, COMB);
    k_gemm<259, 128><<<NATOMS, 64, 0, stream>>>(COMB, op_w1, op_b1, nullptr, Hb, 0);
    k_ln128<<<NATOMS, 128, 0, stream>>>(Hb, op_ln1_g, op_ln1_b, 1);
    k_gemm<128, 128><<<NATOMS, 64, 0, stream>>>(Hb, res_w1, res_b1, nullptr, Rb, 0);
    k_ln128<<<NATOMS, 128, 0, stream>>>(Rb, res_ln_g, res_ln_b, 1);
    k_gemm<128, 128><<<NATOMS, 64, 0, stream>>>(Rb, res_w2, res_b2, Hb, H2, 0);
    k_ln128<<<NATOMS, 128, 0, stream>>>(H2, op_ln2_g, op_ln2_b, 0);
    k_out<<<NATOMS, 128, 0, stream>>>(H2, op_w3, op_b3, coord, bidx, cmin, cmax,
                                      (float*)d_out);
}

// Round 4
// 416.708 us; speedup vs baseline: 1.3228x; 1.3228x over previous
//
#include <hip/hip_runtime.h>
#include <hip/hip_bf16.h>
#include <math.h>
#include <stdint.h>

// Problem constants (fixed by reference)
#define NATOMS 4096
#define HD     128
#define NHEAD  4
#define DHEAD  32
#define FDIM   259
#define BATCH  128
#define H3X    384   // 3*H

typedef __attribute__((ext_vector_type(8))) short short8;
typedef __attribute__((ext_vector_type(4))) float float4v;

// fp32 -> bf16 round-to-nearest-even (values are well-behaved; no NaN path)
__device__ __forceinline__ ushort f2bf(float f) {
    uint32_t u = __float_as_uint(f);
    return (ushort)((u + 0x7fffu + ((u >> 16) & 1u)) >> 16);
}

// block reduction for 128 threads (2 waves)
__device__ __forceinline__ float blk_sum_128(float v, float* scratch) {
#pragma unroll
    for (int o = 32; o; o >>= 1) v += __shfl_down(v, o);
    int lane = threadIdx.x & 63, w = threadIdx.x >> 6;
    if (lane == 0) scratch[w] = v;
    __syncthreads();
    float r = scratch[0] + scratch[1];
    __syncthreads();
    return r;
}

// ---------------- prep: bidx (exact repeat semantics), per-row clamp bounds ----
__global__ void k_prep(const int* __restrict__ num_atoms, const float* __restrict__ cell,
                       int* __restrict__ bidx, float* __restrict__ cmin, float* __restrict__ cmax) {
    __shared__ int start[BATCH + 1];
    int t = threadIdx.x;  // 128 threads
    if (t == 0) {
        int pos = 0;
        for (int b = 0; b < BATCH; b++) { start[b] = pos; pos += num_atoms[b]; }
        start[BATCH] = pos;
    }
    __syncthreads();
    int s = min(start[t], NATOMS), e = min(start[t + 1], NATOMS);
    for (int j = s; j < e; j++) bidx[j] = t;
    if (t == 0) {
        int total = min(start[BATCH], NATOMS);
        for (int j = total; j < NATOMS; j++) bidx[j] = BATCH - 1;  // repeat pads with last value
    }
    for (int rr = t; rr < BATCH * 3; rr += blockDim.x) {
        float a0 = cell[rr * 3 + 0], a1 = cell[rr * 3 + 1], a2 = cell[rr * 3 + 2];
        cmin[rr] = fminf(a0, fminf(a1, a2)) + 1e-6f;
        cmax[rr] = fmaxf(a0, fmaxf(a1, a2)) - 1e-6f;
    }
}

// ---------------- embedding gather + input LayerNorm -> X [N,128] fp32 --------
__global__ void k_embed_ln(const int* __restrict__ elems, const float* __restrict__ emb,
                           const float* __restrict__ g, const float* __restrict__ b,
                           float* __restrict__ X) {
    __shared__ float sc[2];
    int row = blockIdx.x, t = threadIdx.x;
    int e = elems[row];
    float v = emb[e * HD + t];
    float mean = blk_sum_128(v, sc) * (1.f / HD);
    float d = v - mean;
    float var = blk_sum_128(d * d, sc) * (1.f / HD);
    X[row * HD + t] = d * rsqrtf(var + 1e-5f) * g[t] + b[t];
}

// ---------------- generic LN over width 128, in-place, optional silu ----------
__global__ void k_ln128(float* __restrict__ buf, const float* __restrict__ g,
                        const float* __restrict__ b, int silu) {
    __shared__ float sc[2];
    int row = blockIdx.x, t = threadIdx.x;
    float v = buf[row * HD + t];
    float mean = blk_sum_128(v, sc) * (1.f / HD);
    float d = v - mean;
    float var = blk_sum_128(d * d, sc) * (1.f / HD);
    float o = d * rsqrtf(var + 1e-5f) * g[t] + b[t];
    if (silu) o = o / (1.f + __expf(-o));
    buf[row * HD + t] = o;
}

// ---------------- generic row-block GEMM: C[M,N] = A[M,K]fp32 @ W[K,N]fp32 + bias
template <int KDIM, int NDIM>
__global__ void k_gemm(const float* __restrict__ A, const float* __restrict__ W,
                       const float* __restrict__ bias, const float* __restrict__ resid,
                       float* __restrict__ C, int silu) {
    __shared__ float a_s[KDIM];
    int row = blockIdx.x, t = threadIdx.x;
    for (int k = t; k < KDIM; k += blockDim.x) a_s[k] = A[row * KDIM + k];
    __syncthreads();
    int j = t * 2;
    if (j < NDIM) {
        float acc0 = bias[j], acc1 = bias[j + 1];
        const float2* Wp = reinterpret_cast<const float2*>(W);
#pragma unroll 4
        for (int k = 0; k < KDIM; k++) {
            float2 w = Wp[(k * NDIM + j) >> 1];
            float a = a_s[k];
            acc0 += a * w.x;
            acc1 += a * w.y;
        }
        if (resid) { acc0 += resid[row * NDIM + j]; acc1 += resid[row * NDIM + j + 1]; }
        if (silu) {
            acc0 = acc0 / (1.f + __expf(-acc0));
            acc1 = acc1 / (1.f + __expf(-acc1));
        }
        C[row * NDIM + j] = acc0;
        C[row * NDIM + j + 1] = acc1;
    }
}

// ---------------- cell encoder: cf[r] = silu(cell[r]@w1+b1)@w2+b2, rows 0..127 --
__global__ void k_cell(const float* __restrict__ cell, const float* __restrict__ w1,
                       const float* __restrict__ b1, const float* __restrict__ w2,
                       const float* __restrict__ b2, float* __restrict__ CF) {
    __shared__ float hs[HD];
    int r = blockIdx.x, t = threadIdx.x;
    float c0 = cell[r * 3 + 0], c1 = cell[r * 3 + 1], c2 = cell[r * 3 + 2];
    float h = c0 * w1[0 * HD + t] + c1 * w1[1 * HD + t] + c2 * w1[2 * HD + t] + b1[t];
    h = h / (1.f + __expf(-h));
    hs[t] = h;
    __syncthreads();
    float acc = b2[t];
#pragma unroll 8
    for (int k = 0; k < HD; k++) acc += hs[k] * w2[k * HD + t];
    CF[r * HD + t] = acc;
}

// ---------------- MFMA flash attention ----------------------------------------
// Block: 256 thr (4 waves), 64 queries x 1 head. K-chunks of 128 keys staged in
// LDS as bf16: K row-major stride-40 ushort (80B, 16B-aligned, 2-way bank alias
// = free), V transposed stride-136. Scores via mfma_f32_16x16x32_bf16 (K=32 =
// full head dim in ONE mfma). exp in fp32 with constant shift (scores bounded,
// ratios exact); P -> LDS (C-layout -> A-layout transform, m120 pattern) -> PV
// MFMAs. Denominator accumulated fp32 per C-layout row, reduced via shfl_xor.
#define KC 128
#define QT 64
#define MSHIFT 12.0f
__global__ __launch_bounds__(256) void k_attn_mfma(const float* __restrict__ QKV,
                                                   float* __restrict__ ATT) {
    __shared__ alignas(16) ushort K_s[KC * 40];          // [key][dim] stride 40
    __shared__ alignas(16) ushort VT_s[DHEAD * 136];     // [dim][key] stride 136
    __shared__ alignas(16) ushort P_s[4 * 16 * 136];     // per-wave [q][key] stride 136

    const int t = threadIdx.x;
    const int h = blockIdx.y;
    const int q0 = blockIdx.x * QT;
    const int w = t >> 6, lane = t & 63, quad = lane >> 4, lq = lane & 15;

    // Q A-fragment: A[m=lq][k=quad*8+j], query row q0+w*16+lq, pre-scaled
    short8 qf;
    {
        const float* qp = QKV + (size_t)(q0 + w * 16 + lq) * H3X + h * DHEAD + quad * 8;
#pragma unroll
        for (int j = 0; j < 8; j++) qf[j] = (short)f2bf(qp[j] * 0.17677669529663687f);
    }

    float4v O0 = {0.f, 0.f, 0.f, 0.f}, O1 = {0.f, 0.f, 0.f, 0.f};
    float lp[4] = {0.f, 0.f, 0.f, 0.f};
    const int pbase = w * 16 * 136;

    for (int kt = 0; kt < NATOMS; kt += KC) {
        // stage K (row-major) and V (transposed): 1024 float4 / 256 threads
#pragma unroll
        for (int j = 0; j < 4; j++) {
            int i4 = t + 256 * j;
            int r = i4 >> 3, c = (i4 & 7) * 4;
            const float* kp = QKV + (size_t)(kt + r) * H3X + HD + h * DHEAD + c;
            float4 kv = *reinterpret_cast<const float4*>(kp);
            ushort* kd = &K_s[r * 40 + c];
            kd[0] = f2bf(kv.x); kd[1] = f2bf(kv.y); kd[2] = f2bf(kv.z); kd[3] = f2bf(kv.w);
            float4 vv = *reinterpret_cast<const float4*>(kp + HD);
            VT_s[(c + 0) * 136 + r] = f2bf(vv.x);
            VT_s[(c + 1) * 136 + r] = f2bf(vv.y);
            VT_s[(c + 2) * 136 + r] = f2bf(vv.z);
            VT_s[(c + 3) * 136 + r] = f2bf(vv.w);
        }
        __syncthreads();

        // QK^T: 8 key sub-tiles of 16; B[k=dim][n=key] frag = K row read
        float4v S[8];
#pragma unroll
        for (int st = 0; st < 8; st++) {
            short8 kf = *reinterpret_cast<const short8*>(&K_s[(st * 16 + lq) * 40 + quad * 8]);
            float4v z = {0.f, 0.f, 0.f, 0.f};
            S[st] = __builtin_amdgcn_mfma_f32_16x16x32_bf16(qf, kf, z, 0, 0, 0);
        }
        // exp (C-layout: row=quad*4+r, col=lq+16*st) + denominators + P to LDS
#pragma unroll
        for (int st = 0; st < 8; st++) {
#pragma unroll
            for (int r = 0; r < 4; r++) {
                float p = __expf(S[st][r] - MSHIFT);
                lp[r] += p;
                P_s[pbase + (quad * 4 + r) * 136 + st * 16 + lq] = f2bf(p);
            }
        }
        // PV: A[m=lq][k] from P_s, B[k=key][n=dim] from VT_s; 4 key-quarters
#pragma unroll
        for (int kh = 0; kh < 4; kh++) {
            short8 pf = *reinterpret_cast<const short8*>(&P_s[pbase + lq * 136 + kh * 32 + quad * 8]);
            short8 v0 = *reinterpret_cast<const short8*>(&VT_s[lq * 136 + kh * 32 + quad * 8]);
            short8 v1 = *reinterpret_cast<const short8*>(&VT_s[(16 + lq) * 136 + kh * 32 + quad * 8]);
            O0 = __builtin_amdgcn_mfma_f32_16x16x32_bf16(pf, v0, O0, 0, 0, 0);
            O1 = __builtin_amdgcn_mfma_f32_16x16x32_bf16(pf, v1, O1, 0, 0, 0);
        }
        __syncthreads();  // before next chunk overwrites K_s/VT_s
    }

    // reduce denominators across the 16 column-lanes of each quad
#pragma unroll
    for (int r = 0; r < 4; r++) {
#pragma unroll
        for (int m = 1; m < 16; m <<= 1) lp[r] += __shfl_xor(lp[r], m);
    }
    // write O (C-layout row=quad*4+r, col=lq), normalized
#pragma unroll
    for (int r = 0; r < 4; r++) {
        float inv = 1.f / lp[r];
        int row = q0 + w * 16 + quad * 4 + r;
        ATT[(size_t)row * HD + h * DHEAD + lq] = O0[r] * inv;
        ATT[(size_t)row * HD + h * DHEAD + 16 + lq] = O1[r] * inv;
    }
}

// ---------------- concat [x1 | cf[bidx] | coord] + LN over F=259 ---------------
__global__ void k_comb(const float* __restrict__ X1, const float* __restrict__ CF,
                       const float* __restrict__ coord, const int* __restrict__ bidx,
                       const float* __restrict__ g, const float* __restrict__ b,
                       float* __restrict__ COMB) {
    __shared__ float sc[2];
    int row = blockIdx.x, t = threadIdx.x;
    int bi = bidx[row];
    float v0 = X1[row * HD + t];
    float v1 = CF[bi * HD + t];
    float v2 = (t < 3) ? coord[row * 3 + t] : 0.f;
    float tot = blk_sum_128(v0 + v1 + v2, sc);
    float mean = tot * (1.f / FDIM);
    float d0 = v0 - mean, d1 = v1 - mean, d2 = (t < 3) ? (v2 - mean) : 0.f;
    float var = blk_sum_128(d0 * d0 + d1 * d1 + d2 * d2, sc) * (1.f / FDIM);
    float inv = rsqrtf(var + 1e-5f);
    COMB[row * FDIM + t] = d0 * inv * g[t] + b[t];
    COMB[row * FDIM + 128 + t] = d1 * inv * g[128 + t] + b[128 + t];
    if (t < 3) COMB[row * FDIM + 256 + t] = d2 * inv * g[256 + t] + b[256 + t];
}

// ---------------- final: offset = tanh(h@w3+b3)*0.01; clip(coord+offset) -------
// OUTPUT IS FLOAT32 (reference returns float32; harness reads np.float32).
__global__ void k_out(const float* __restrict__ Hf, const float* __restrict__ w3,
                      const float* __restrict__ b3, const float* __restrict__ coord,
                      const int* __restrict__ bidx, const float* __restrict__ cmin,
                      const float* __restrict__ cmax, float* __restrict__ out) {
    __shared__ float sc[2];
    __shared__ float offs[3];
    int row = blockIdx.x, t = threadIdx.x;
    float hv = Hf[row * HD + t];
    for (int c = 0; c < 3; c++) {
        float tot = blk_sum_128(hv * w3[t * 3 + c], sc);
        if (t == 0) offs[c] = tanhf(tot + b3[c]) * 0.01f;
    }
    __syncthreads();
    if (t < 3) {
        int bi = bidx[row];
        float pert = coord[row * 3 + t] + offs[t];
        pert = fminf(fmaxf(pert, cmin[bi * 3 + t]), cmax[bi * 3 + t]);
        out[row * 3 + t] = pert;
    }
}

extern "C" void kernel_launch(void* const* d_in, const int* in_sizes, int n_in,
                              void* d_out, int out_size, void* d_ws, size_t ws_size,
                              hipStream_t stream) {
    const int* num_atoms = (const int*)d_in[0];
    const int* elems = (const int*)d_in[1];
    const float* cell = (const float*)d_in[2];
    const float* coord = (const float*)d_in[3];
    const float* emb = (const float*)d_in[4];
    const float* ln_in_g = (const float*)d_in[5];
    const float* ln_in_b = (const float*)d_in[6];
    const float* attn_in_w = (const float*)d_in[7];
    const float* attn_in_b = (const float*)d_in[8];
    const float* attn_out_w = (const float*)d_in[9];
    const float* attn_out_b = (const float*)d_in[10];
    const float* ce_w1 = (const float*)d_in[11];
    const float* ce_b1 = (const float*)d_in[12];
    const float* ce_w2 = (const float*)d_in[13];
    const float* ce_b2 = (const float*)d_in[14];
    const float* ln_feat_g = (const float*)d_in[15];
    const float* ln_feat_b = (const float*)d_in[16];
    const float* op_w1 = (const float*)d_in[17];
    const float* op_b1 = (const float*)d_in[18];
    const float* op_ln1_g = (const float*)d_in[19];
    const float* op_ln1_b = (const float*)d_in[20];
    const float* res_w1 = (const float*)d_in[21];
    const float* res_b1 = (const float*)d_in[22];
    const float* res_ln_g = (const float*)d_in[23];
    const float* res_ln_b = (const float*)d_in[24];
    const float* res_w2 = (const float*)d_in[25];
    const float* res_b2 = (const float*)d_in[26];
    const float* op_ln2_g = (const float*)d_in[27];
    const float* op_ln2_b = (const float*)d_in[28];
    const float* op_w3 = (const float*)d_in[29];
    const float* op_b3 = (const float*)d_in[30];

    // workspace layout (~12.1 MB total, all fp32, lifetimes tracked for reuse):
    char* ws = (char*)d_ws;
    float* X = (float*)(ws + 0);                    // slot0 2MB: X, later ATT
    float* QKV = (float*)(ws + (2u << 20));         // slot1 6MB: QKV -> COMB -> R
    float* ATT = X;
    float* X1 = (float*)(ws + (8u << 20));          // slot2 2MB: X1 -> H2
    float* COMB = QKV;
    float* Hb = (float*)(ws + (10u << 20));         // slot3 2MB: H
    float* Rb = QKV;
    float* H2 = X1;
    int* bidx = (int*)(ws + (12u << 20));           // 16KB
    float* cmin = (float*)(ws + (12u << 20) + 16384);
    float* cmax = cmin + BATCH * 3;
    float* CF = (float*)(ws + (12u << 20) + 20480); // 64KB

    k_prep<<<1, 128, 0, stream>>>(num_atoms, cell, bidx, cmin, cmax);
    k_embed_ln<<<NATOMS, 128, 0, stream>>>(elems, emb, ln_in_g, ln_in_b, X);
    k_gemm<128, 384><<<NATOMS, 192, 0, stream>>>(X, attn_in_w, attn_in_b, nullptr, QKV, 0);
    k_attn_mfma<<<dim3(NATOMS / QT, NHEAD), 256, 0, stream>>>(QKV, ATT);
    k_gemm<128, 128><<<NATOMS, 64, 0, stream>>>(ATT, attn_out_w, attn_out_b, nullptr, X1, 0);
    k_cell<<<BATCH, 128, 0, stream>>>(cell, ce_w1, ce_b1, ce_w2, ce_b2, CF);
    k_comb<<<NATOMS, 128, 0, stream>>>(X1, CF, coord, bidx, ln_feat_g, ln_feat_b, COMB);
    k_gemm<259, 128><<<NATOMS, 64, 0, stream>>>(COMB, op_w1, op_b1, nullptr, Hb, 0);
    k_ln128<<<NATOMS, 128, 0, stream>>>(Hb, op_ln1_g, op_ln1_b, 1);
    k_gemm<128, 128><<<NATOMS, 64, 0, stream>>>(Hb, res_w1, res_b1, nullptr, Rb, 0);
    k_ln128<<<NATOMS, 128, 0, stream>>>(Rb, res_ln_g, res_ln_b, 1);
    k_gemm<128, 128><<<NATOMS, 64, 0, stream>>>(Rb, res_w2, res_b2, Hb, H2, 0);
    k_ln128<<<NATOMS, 128, 0, stream>>>(H2, op_ln2_g, op_ln2_b, 0);
    k_out<<<NATOMS, 128, 0, stream>>>(H2, op_w3, op_b3, coord, bidx, cmin, cmax,
                                      (float*)d_out);
}

// Round 5
// 221.100 us; speedup vs baseline: 2.4931x; 1.8847x over previous
//
#include <hip/hip_runtime.h>
#include <hip/hip_bf16.h>
#include <math.h>
#include <stdint.h>

// Problem constants (fixed by reference)
#define NATOMS 4096
#define HD     128
#define NHEAD  4
#define DHEAD  32
#define FDIM   259
#define BATCH  128
#define H3X    384
#define SPLIT  4
#define KC     128
#define MSHIFT 12.0f

typedef __attribute__((ext_vector_type(8))) short short8;
typedef __attribute__((ext_vector_type(4))) float float4v;

__device__ __forceinline__ ushort f2bf(float f) {
    uint32_t u = __float_as_uint(f);
    return (ushort)((u + 0x7fffu + ((u >> 16) & 1u)) >> 16);
}
__device__ __forceinline__ float b2f(ushort u) {
    return __uint_as_float(((uint32_t)u) << 16);
}

// block reduction for 128 threads (2 waves)
__device__ __forceinline__ float blk_sum_128(float v, float* scratch) {
#pragma unroll
    for (int o = 32; o; o >>= 1) v += __shfl_down(v, o);
    int lane = threadIdx.x & 63, w = threadIdx.x >> 6;
    if (lane == 0) scratch[w] = v;
    __syncthreads();
    float r = scratch[0] + scratch[1];
    __syncthreads();
    return r;
}

// ---------------- prep: bidx + clamp bounds -----------------------------------
__global__ void k_prep(const int* __restrict__ num_atoms, const float* __restrict__ cell,
                       int* __restrict__ bidx, float* __restrict__ cmin, float* __restrict__ cmax) {
    __shared__ int start[BATCH + 1];
    int t = threadIdx.x;
    if (t == 0) {
        int pos = 0;
        for (int b = 0; b < BATCH; b++) { start[b] = pos; pos += num_atoms[b]; }
        start[BATCH] = pos;
    }
    __syncthreads();
    int s = min(start[t], NATOMS), e = min(start[t + 1], NATOMS);
    for (int j = s; j < e; j++) bidx[j] = t;
    if (t == 0) {
        int total = min(start[BATCH], NATOMS);
        for (int j = total; j < NATOMS; j++) bidx[j] = BATCH - 1;
    }
    for (int rr = t; rr < BATCH * 3; rr += blockDim.x) {
        float a0 = cell[rr * 3 + 0], a1 = cell[rr * 3 + 1], a2 = cell[rr * 3 + 2];
        cmin[rr] = fminf(a0, fminf(a1, a2)) + 1e-6f;
        cmax[rr] = fmaxf(a0, fmaxf(a1, a2)) - 1e-6f;
    }
}

// ---------------- pack all weights to bf16, transposed [n][k] -----------------
__global__ void k_packw(const float* __restrict__ qkvw, const float* __restrict__ aow,
                        const float* __restrict__ op1w, const float* __restrict__ r1w,
                        const float* __restrict__ r2w,
                        ushort* __restrict__ Wqkv, ushort* __restrict__ Wao,
                        ushort* __restrict__ Wop1, ushort* __restrict__ Wr1,
                        ushort* __restrict__ Wr2) {
    int idx = blockIdx.x * 256 + threadIdx.x;  // 528*256 = 135168
    if (idx < 49152) {                          // [384][128]
        int n = idx >> 7, k = idx & 127;
        Wqkv[idx] = f2bf(qkvw[k * H3X + n]);
    } else if (idx < 65536) {
        int j = idx - 49152; int n = j >> 7, k = j & 127;
        Wao[j] = f2bf(aow[k * HD + n]);
    } else if (idx < 102400) {                  // [128][288], zero-pad k>=259
        int j = idx - 65536; int n = j / 288, k = j - n * 288;
        Wop1[j] = (k < FDIM) ? f2bf(op1w[k * HD + n]) : (ushort)0;
    } else if (idx < 118784) {
        int j = idx - 102400; int n = j >> 7, k = j & 127;
        Wr1[j] = f2bf(r1w[k * HD + n]);
    } else if (idx < 135168) {
        int j = idx - 118784; int n = j >> 7, k = j & 127;
        Wr2[j] = f2bf(r2w[k * HD + n]);
    }
}

// ---------------- embedding gather + input LayerNorm -> Xb bf16 ---------------
__global__ void k_embed_ln(const int* __restrict__ elems, const float* __restrict__ emb,
                           const float* __restrict__ g, const float* __restrict__ b,
                           ushort* __restrict__ Xb) {
    __shared__ float sc[2];
    int row = blockIdx.x, t = threadIdx.x;
    int e = elems[row];
    float v = emb[e * HD + t];
    float mean = blk_sum_128(v, sc) * (1.f / HD);
    float d = v - mean;
    float var = blk_sum_128(d * d, sc) * (1.f / HD);
    Xb[row * HD + t] = f2bf(d * rsqrtf(var + 1e-5f) * g[t] + b[t]);
}

// ---------------- cell encoder (fp32, tiny) -----------------------------------
__global__ void k_cell(const float* __restrict__ cell, const float* __restrict__ w1,
                       const float* __restrict__ b1, const float* __restrict__ w2,
                       const float* __restrict__ b2, float* __restrict__ CF) {
    __shared__ float hs[HD];
    int r = blockIdx.x, t = threadIdx.x;
    float c0 = cell[r * 3 + 0], c1 = cell[r * 3 + 1], c2 = cell[r * 3 + 2];
    float h = c0 * w1[0 * HD + t] + c1 * w1[1 * HD + t] + c2 * w1[2 * HD + t] + b1[t];
    h = h / (1.f + __expf(-h));
    hs[t] = h;
    __syncthreads();
    float acc = b2[t];
#pragma unroll 8
    for (int k = 0; k < HD; k++) acc += hs[k] * w2[k * HD + t];
    CF[r * HD + t] = acc;
}

// ---------------- QKV GEMM (MFMA) + pack Qb (scaled), Kb, VTb -----------------
// block = 256 thr (4 waves); wave = 16 rows x 384 cols; grid 64.
__global__ __launch_bounds__(256) void k_qkv(const ushort* __restrict__ A,
                                             const ushort* __restrict__ Wt,
                                             const float* __restrict__ bias,
                                             ushort* __restrict__ Qb, ushort* __restrict__ Kb,
                                             ushort* __restrict__ VTb) {
    __shared__ alignas(16) ushort vt_tmp[4][128][16];
    const int t = threadIdx.x, w = t >> 6, lane = t & 63, quad = lane >> 4, lq = lane & 15;
    const int rowbase = blockIdx.x * 64 + w * 16;
    float4v acc[24];
#pragma unroll
    for (int i = 0; i < 24; i++) acc[i] = (float4v){0.f, 0.f, 0.f, 0.f};
#pragma unroll
    for (int kt = 0; kt < 4; kt++) {
        short8 af = *(const short8*)(A + (rowbase + lq) * HD + kt * 32 + quad * 8);
#pragma unroll
        for (int nt = 0; nt < 24; nt++) {
            short8 wf = *(const short8*)(Wt + (lq + 16 * nt) * HD + kt * 32 + quad * 8);
            acc[nt] = __builtin_amdgcn_mfma_f32_16x16x32_bf16(af, wf, acc[nt], 0, 0, 0);
        }
    }
#pragma unroll
    for (int nt = 0; nt < 24; nt++) {
        int col = lq + 16 * nt;
        float bb = bias[col];
#pragma unroll
        for (int r = 0; r < 4; r++) {
            float c = acc[nt][r] + bb;
            int row = rowbase + quad * 4 + r;
            if (nt < 8) {
                Qb[(((col >> 5) * NATOMS) + row) * 32 + (col & 31)] =
                    f2bf(c * 0.17677669529663687f);
            } else if (nt < 16) {
                int cc = col - 128;
                Kb[(((cc >> 5) * NATOMS) + row) * 32 + (cc & 31)] = f2bf(c);
            } else {
                int cc = col - 256;
                vt_tmp[w][cc][quad * 4 + r] = f2bf(c);  // per-wave transpose buffer
            }
        }
    }
    // flush V transpose: 128 (h,d) rows x 16 atoms, 16B stores (per-wave, no barrier)
#pragma unroll
    for (int pass = 0; pass < 2; pass++) {
        int cc = lane + 64 * pass;
        int hh = cc >> 5, d = cc & 31;
        uint4 a0 = *(const uint4*)&vt_tmp[w][cc][0];
        uint4 a1 = *(const uint4*)&vt_tmp[w][cc][8];
        ushort* dst = VTb + (size_t)(hh * 32 + d) * NATOMS + rowbase;
        *(uint4*)(dst) = a0;
        *(uint4*)(dst + 8) = a1;
    }
}

// ---------------- attention, split-K: grid (64 qtiles, 4 heads, 4 splits) -----
__global__ __launch_bounds__(256) void k_attn(const ushort* __restrict__ Qb,
                                              const ushort* __restrict__ Kb,
                                              const ushort* __restrict__ VTb,
                                              ushort* __restrict__ Opart,
                                              float* __restrict__ lpart) {
    __shared__ alignas(16) ushort K_s[KC * 40];
    __shared__ alignas(16) ushort VT_s[DHEAD * 136];
    __shared__ alignas(16) ushort P_s[4 * 16 * 136];
    const int t = threadIdx.x, w = t >> 6, lane = t & 63, quad = lane >> 4, lq = lane & 15;
    const int h = blockIdx.y, sp = blockIdx.z, q0 = blockIdx.x * 64;
    const int rq = q0 + w * 16 + lq;
    short8 qf = *(const short8*)(Qb + (size_t)(h * NATOMS + rq) * 32 + quad * 8);
    float4v O0 = {0.f, 0.f, 0.f, 0.f}, O1 = {0.f, 0.f, 0.f, 0.f};
    float lp[4] = {0.f, 0.f, 0.f, 0.f};
    const int pb = w * 16 * 136;

    for (int ck = 0; ck < (NATOMS / SPLIT) / KC; ck++) {
        int kb = sp * (NATOMS / SPLIT) + ck * KC;
        // stage K rows (64B each) and VT rows (256B each): pure 16B copies
#pragma unroll
        for (int j = 0; j < 2; j++) {
            int idx = t + 256 * j;
            int r = idx >> 2, sg = idx & 3;
            *(uint4*)(K_s + r * 40 + sg * 8) =
                *(const uint4*)(Kb + (size_t)(h * NATOMS + kb + r) * 32 + sg * 8);
            int d = idx >> 4, sg2 = idx & 15;
            *(uint4*)(VT_s + d * 136 + sg2 * 8) =
                *(const uint4*)(VTb + (size_t)(h * 32 + d) * NATOMS + kb + sg2 * 8);
        }
        __syncthreads();
        float4v S[8];
#pragma unroll
        for (int st = 0; st < 8; st++) {
            short8 kf = *(const short8*)(K_s + (st * 16 + lq) * 40 + quad * 8);
            float4v z = {0.f, 0.f, 0.f, 0.f};
            S[st] = __builtin_amdgcn_mfma_f32_16x16x32_bf16(qf, kf, z, 0, 0, 0);
        }
#pragma unroll
        for (int st = 0; st < 8; st++) {
#pragma unroll
            for (int r = 0; r < 4; r++) {
                float p = __expf(S[st][r] - MSHIFT);
                lp[r] += p;
                P_s[pb + (quad * 4 + r) * 136 + st * 16 + lq] = f2bf(p);
            }
        }
#pragma unroll
        for (int kh = 0; kh < 4; kh++) {
            short8 pf = *(const short8*)(P_s + pb + lq * 136 + kh * 32 + quad * 8);
            short8 v0 = *(const short8*)(VT_s + lq * 136 + kh * 32 + quad * 8);
            short8 v1 = *(const short8*)(VT_s + (16 + lq) * 136 + kh * 32 + quad * 8);
            O0 = __builtin_amdgcn_mfma_f32_16x16x32_bf16(pf, v0, O0, 0, 0, 0);
            O1 = __builtin_amdgcn_mfma_f32_16x16x32_bf16(pf, v1, O1, 0, 0, 0);
        }
        __syncthreads();
    }
#pragma unroll
    for (int r = 0; r < 4; r++) {
#pragma unroll
        for (int m = 1; m < 16; m <<= 1) lp[r] += __shfl_xor(lp[r], m);
        int row = q0 + w * 16 + quad * 4 + r;
        Opart[(size_t)(sp * NATOMS + row) * HD + h * 32 + lq] = f2bf(O0[r]);
        Opart[(size_t)(sp * NATOMS + row) * HD + h * 32 + 16 + lq] = f2bf(O1[r]);
        if (lq == 0) lpart[sp * (NHEAD * NATOMS) + h * NATOMS + row] = lp[r];
    }
}

// ---------------- combine split partials -> ATTb bf16 -------------------------
__global__ void k_att_comb(const ushort* __restrict__ Opart, const float* __restrict__ lpart,
                           ushort* __restrict__ ATTb) {
    int idx = blockIdx.x * 256 + threadIdx.x;  // 4096*128 / 256 = 2048 blocks
    int row = idx >> 7, col = idx & 127, h = col >> 5;
    float o = 0.f, l = 0.f;
#pragma unroll
    for (int s = 0; s < SPLIT; s++) {
        o += b2f(Opart[(size_t)(s * NATOMS + row) * HD + col]);
        l += lpart[s * (NHEAD * NATOMS) + h * NATOMS + row];
    }
    ATTb[idx] = f2bf(o / l);
}

// ---------------- MFMA GEMM, N=128, fused epilogues ---------------------------
// EPI 0: bias -> bf16.  EPI 1: bias+LN+silu -> bf16.  EPI 2: bias+resid+LN -> bf16.
template <int KP, int EPI>
__global__ __launch_bounds__(256) void k_gemm_mfma(const ushort* __restrict__ A,
                                                   const ushort* __restrict__ Wt,
                                                   const float* __restrict__ bias,
                                                   const float* __restrict__ lg,
                                                   const float* __restrict__ lb,
                                                   const ushort* __restrict__ resid,
                                                   ushort* __restrict__ out) {
    const int t = threadIdx.x, w = t >> 6, lane = t & 63, quad = lane >> 4, lq = lane & 15;
    const int rowbase = blockIdx.x * 64 + w * 16;
    float4v acc[8];
#pragma unroll
    for (int i = 0; i < 8; i++) acc[i] = (float4v){0.f, 0.f, 0.f, 0.f};
#pragma unroll
    for (int kt = 0; kt < KP / 32; kt++) {
        short8 af = *(const short8*)(A + (size_t)(rowbase + lq) * KP + kt * 32 + quad * 8);
#pragma unroll
        for (int nt = 0; nt < 8; nt++) {
            short8 wf = *(const short8*)(Wt + (size_t)(lq + 16 * nt) * KP + kt * 32 + quad * 8);
            acc[nt] = __builtin_amdgcn_mfma_f32_16x16x32_bf16(af, wf, acc[nt], 0, 0, 0);
        }
    }
    float c[8][4];
#pragma unroll
    for (int nt = 0; nt < 8; nt++) {
        float bb = bias[lq + 16 * nt];
#pragma unroll
        for (int r = 0; r < 4; r++) c[nt][r] = acc[nt][r] + bb;
    }
    if constexpr (EPI == 2) {
#pragma unroll
        for (int nt = 0; nt < 8; nt++)
#pragma unroll
            for (int r = 0; r < 4; r++)
                c[nt][r] += b2f(resid[(size_t)(rowbase + quad * 4 + r) * HD + lq + 16 * nt]);
    }
    if constexpr (EPI == 0) {
#pragma unroll
        for (int r = 0; r < 4; r++) {
            int row = rowbase + quad * 4 + r;
#pragma unroll
            for (int nt = 0; nt < 8; nt++)
                out[(size_t)row * HD + lq + 16 * nt] = f2bf(c[nt][r]);
        }
    } else {
#pragma unroll
        for (int r = 0; r < 4; r++) {
            float s1 = 0.f, s2 = 0.f;
#pragma unroll
            for (int nt = 0; nt < 8; nt++) { s1 += c[nt][r]; s2 += c[nt][r] * c[nt][r]; }
#pragma unroll
            for (int m = 1; m < 16; m <<= 1) { s1 += __shfl_xor(s1, m); s2 += __shfl_xor(s2, m); }
            float mean = s1 * (1.f / HD);
            float var = s2 * (1.f / HD) - mean * mean;
            float inv = rsqrtf(var + 1e-5f);
            int row = rowbase + quad * 4 + r;
#pragma unroll
            for (int nt = 0; nt < 8; nt++) {
                int col = lq + 16 * nt;
                float o = (c[nt][r] - mean) * inv * lg[col] + lb[col];
                if constexpr (EPI == 1) o = o / (1.f + __expf(-o));
                out[(size_t)row * HD + col] = f2bf(o);
            }
        }
    }
}

// ---------------- concat [x1 | cf[bidx] | coord] + LN(F=259) -> COMBb[4096][288]
__global__ void k_comb(const ushort* __restrict__ X1b, const float* __restrict__ CF,
                       const float* __restrict__ coord, const int* __restrict__ bidx,
                       const float* __restrict__ g, const float* __restrict__ b,
                       ushort* __restrict__ COMBb) {
    __shared__ float sc[2];
    int row = blockIdx.x, t = threadIdx.x;
    int bi = bidx[row];
    float v0 = b2f(X1b[row * HD + t]);
    float v1 = CF[bi * HD + t];
    float v2 = (t < 3) ? coord[row * 3 + t] : 0.f;
    float tot = blk_sum_128(v0 + v1 + v2, sc);
    float mean = tot * (1.f / FDIM);
    float d0 = v0 - mean, d1 = v1 - mean, d2 = (t < 3) ? (v2 - mean) : 0.f;
    float var = blk_sum_128(d0 * d0 + d1 * d1 + d2 * d2, sc) * (1.f / FDIM);
    float inv = rsqrtf(var + 1e-5f);
    COMBb[row * 288 + t] = f2bf(d0 * inv * g[t] + b[t]);
    COMBb[row * 288 + 128 + t] = f2bf(d1 * inv * g[128 + t] + b[128 + t]);
    if (t < 3) COMBb[row * 288 + 256 + t] = f2bf(d2 * inv * g[256 + t] + b[256 + t]);
    if (t >= 3 && t < 32) COMBb[row * 288 + 256 + t] = 0;  // zero pad 259..287
}

// ---------------- final: offset = tanh(h@w3+b3)*0.01; clip --------------------
__global__ void k_out(const ushort* __restrict__ H2b, const float* __restrict__ w3,
                      const float* __restrict__ b3, const float* __restrict__ coord,
                      const int* __restrict__ bidx, const float* __restrict__ cmin,
                      const float* __restrict__ cmax, float* __restrict__ out) {
    __shared__ float sc[2];
    __shared__ float offs[3];
    int row = blockIdx.x, t = threadIdx.x;
    float hv = b2f(H2b[row * HD + t]);
    for (int c = 0; c < 3; c++) {
        float tot = blk_sum_128(hv * w3[t * 3 + c], sc);
        if (t == 0) offs[c] = tanhf(tot + b3[c]) * 0.01f;
    }
    __syncthreads();
    if (t < 3) {
        int bi = bidx[row];
        float pert = coord[row * 3 + t] + offs[t];
        pert = fminf(fmaxf(pert, cmin[bi * 3 + t]), cmax[bi * 3 + t]);
        out[row * 3 + t] = pert;
    }
}

extern "C" void kernel_launch(void* const* d_in, const int* in_sizes, int n_in,
                              void* d_out, int out_size, void* d_ws, size_t ws_size,
                              hipStream_t stream) {
    const int* num_atoms = (const int*)d_in[0];
    const int* elems = (const int*)d_in[1];
    const float* cell = (const float*)d_in[2];
    const float* coord = (const float*)d_in[3];
    const float* emb = (const float*)d_in[4];
    const float* ln_in_g = (const float*)d_in[5];
    const float* ln_in_b = (const float*)d_in[6];
    const float* attn_in_w = (const float*)d_in[7];
    const float* attn_in_b = (const float*)d_in[8];
    const float* attn_out_w = (const float*)d_in[9];
    const float* attn_out_b = (const float*)d_in[10];
    const float* ce_w1 = (const float*)d_in[11];
    const float* ce_b1 = (const float*)d_in[12];
    const float* ce_w2 = (const float*)d_in[13];
    const float* ce_b2 = (const float*)d_in[14];
    const float* ln_feat_g = (const float*)d_in[15];
    const float* ln_feat_b = (const float*)d_in[16];
    const float* op_w1 = (const float*)d_in[17];
    const float* op_b1 = (const float*)d_in[18];
    const float* op_ln1_g = (const float*)d_in[19];
    const float* op_ln1_b = (const float*)d_in[20];
    const float* res_w1 = (const float*)d_in[21];
    const float* res_b1 = (const float*)d_in[22];
    const float* res_ln_g = (const float*)d_in[23];
    const float* res_ln_b = (const float*)d_in[24];
    const float* res_w2 = (const float*)d_in[25];
    const float* res_b2 = (const float*)d_in[26];
    const float* op_ln2_g = (const float*)d_in[27];
    const float* op_ln2_b = (const float*)d_in[28];
    const float* op_w3 = (const float*)d_in[29];
    const float* op_b3 = (const float*)d_in[30];

    // workspace layout (~11.6 MB; round-3 used 12.1 MB successfully)
    char* ws = (char*)d_ws;
    const size_t MB = 1u << 20;
    ushort* Xb = (ushort*)(ws);                    // [0,1M) — dead after k_qkv
    ushort* ATTb = (ushort*)(ws);                  // reuse [0,1M)
    ushort* Qb = (ushort*)(ws + 1 * MB);
    ushort* Kb = (ushort*)(ws + 2 * MB);
    ushort* VTb = (ushort*)(ws + 3 * MB);
    ushort* Opart = (ushort*)(ws + 4 * MB);        // [4M,8M) — dead after combine
    ushort* X1b = (ushort*)(ws + 4 * MB);          // reuse
    ushort* COMBb = (ushort*)(ws + 5 * MB);        // [5M,7.25M) reuse
    float* lpart = (float*)(ws + 8 * MB);          // 256 KB
    ushort* Hb = (ushort*)(ws + 8 * MB + (256 << 10));
    ushort* Rb = (ushort*)(ws + 9 * MB + (256 << 10));
    ushort* H2b = (ushort*)(ws + 10 * MB + (256 << 10));
    int* bidx = (int*)(ws + 11 * MB + (256 << 10));
    float* cmin = (float*)(ws + 11 * MB + (272 << 10));
    float* cmax = (float*)(ws + 11 * MB + (274 << 10));
    float* CF = (float*)(ws + 11 * MB + (276 << 10));
    ushort* Wqkv = (ushort*)(ws + 11 * MB + (344 << 10));
    ushort* Wao = (ushort*)(ws + 11 * MB + (440 << 10));
    ushort* Wop1 = (ushort*)(ws + 11 * MB + (472 << 10));
    ushort* Wr1 = (ushort*)(ws + 11 * MB + (544 << 10));
    ushort* Wr2 = (ushort*)(ws + 11 * MB + (576 << 10));

    k_prep<<<1, 128, 0, stream>>>(num_atoms, cell, bidx, cmin, cmax);
    k_packw<<<528, 256, 0, stream>>>(attn_in_w, attn_out_w, op_w1, res_w1, res_w2,
                                     Wqkv, Wao, Wop1, Wr1, Wr2);
    k_cell<<<BATCH, 128, 0, stream>>>(cell, ce_w1, ce_b1, ce_w2, ce_b2, CF);
    k_embed_ln<<<NATOMS, 128, 0, stream>>>(elems, emb, ln_in_g, ln_in_b, Xb);
    k_qkv<<<64, 256, 0, stream>>>(Xb, Wqkv, attn_in_b, Qb, Kb, VTb);
    k_attn<<<dim3(NATOMS / 64, NHEAD, SPLIT), 256, 0, stream>>>(Qb, Kb, VTb, Opart, lpart);
    k_att_comb<<<(NATOMS * HD) / 256, 256, 0, stream>>>(Opart, lpart, ATTb);
    k_gemm_mfma<128, 0><<<64, 256, 0, stream>>>(ATTb, Wao, attn_out_b, nullptr, nullptr,
                                                nullptr, X1b);
    k_comb<<<NATOMS, 128, 0, stream>>>(X1b, CF, coord, bidx, ln_feat_g, ln_feat_b, COMBb);
    k_gemm_mfma<288, 1><<<64, 256, 0, stream>>>(COMBb, Wop1, op_b1, op_ln1_g, op_ln1_b,
                                                nullptr, Hb);
    k_gemm_mfma<128, 1><<<64, 256, 0, stream>>>(Hb, Wr1, res_b1, res_ln_g, res_ln_b,
                                                nullptr, Rb);
    k_gemm_mfma<128, 2><<<64, 256, 0, stream>>>(Rb, Wr2, res_b2, op_ln2_g, op_ln2_b,
                                                Hb, H2b);
    k_out<<<NATOMS, 128, 0, stream>>>(H2b, op_w3, op_b3, coord, bidx, cmin, cmax,
                                      (float*)d_out);
}

// Round 6
// 214.861 us; speedup vs baseline: 2.5655x; 1.0290x over previous
//
#include <hip/hip_runtime.h>
#include <hip/hip_bf16.h>
#include <math.h>
#include <stdint.h>

#define NATOMS 4096
#define HD     128
#define NHEAD  4
#define DHEAD  32
#define FDIM   259
#define BATCH  128
#define H3X    384
#define SPLIT  4

typedef __attribute__((ext_vector_type(8))) short short8;
typedef __attribute__((ext_vector_type(4))) float float4v;
typedef __attribute__((ext_vector_type(16))) float f32x16;

__device__ __forceinline__ ushort f2bf(float f) {
    uint32_t u = __float_as_uint(f);
    return (ushort)((u + 0x7fffu + ((u >> 16) & 1u)) >> 16);
}
__device__ __forceinline__ float b2f(ushort u) {
    return __uint_as_float(((uint32_t)u) << 16);
}
__device__ __forceinline__ f32x16 z16() {
    f32x16 v;
#pragma unroll
    for (int i = 0; i < 16; i++) v[i] = 0.f;
    return v;
}

// block reduction for 128 threads (2 waves)
__device__ __forceinline__ float blk_sum_128(float v, float* scratch) {
#pragma unroll
    for (int o = 32; o; o >>= 1) v += __shfl_down(v, o);
    int lane = threadIdx.x & 63, w = threadIdx.x >> 6;
    if (lane == 0) scratch[w] = v;
    __syncthreads();
    float r = scratch[0] + scratch[1];
    __syncthreads();
    return r;
}

// ---------------- setup: embed+LN | weight pack | cell MLP | prep -------------
// grid: [0,1024) embed (4 rows/block, wave-per-row); [1024,1552) packw;
// [1552,1680) cell; 1680 prep.  All independent.
#define NB_EMB 1024
#define NB_PACK 528
#define NB_CELL 128
__global__ __launch_bounds__(256) void k_setup(
        const int* __restrict__ num_atoms, const float* __restrict__ cell,
        const int* __restrict__ elems, const float* __restrict__ emb,
        const float* __restrict__ ln_in_g, const float* __restrict__ ln_in_b,
        const float* __restrict__ qkvw, const float* __restrict__ aow,
        const float* __restrict__ op1w, const float* __restrict__ r1w,
        const float* __restrict__ r2w,
        const float* __restrict__ ce_w1, const float* __restrict__ ce_b1,
        const float* __restrict__ ce_w2, const float* __restrict__ ce_b2,
        int* __restrict__ bidx, float* __restrict__ cmin, float* __restrict__ cmax,
        ushort* __restrict__ Xb, ushort* __restrict__ Wqkv, ushort* __restrict__ Wao,
        ushort* __restrict__ Wop1, ushort* __restrict__ Wr1, ushort* __restrict__ Wr2,
        float* __restrict__ CF) {
    __shared__ float hs[HD];
    __shared__ int start[BATCH + 1];
    const int t = threadIdx.x, w = t >> 6, lane = t & 63;
    if (blockIdx.x < NB_EMB) {
        int row = blockIdx.x * 4 + w;
        int e = elems[row];
        float v0 = emb[e * HD + lane], v1 = emb[e * HD + 64 + lane];
        float s = v0 + v1, ss = v0 * v0 + v1 * v1;
#pragma unroll
        for (int m = 1; m < 64; m <<= 1) { s += __shfl_xor(s, m); ss += __shfl_xor(ss, m); }
        float mean = s * (1.f / HD);
        float var = ss * (1.f / HD) - mean * mean;
        float inv = rsqrtf(var + 1e-5f);
        Xb[row * HD + lane] = f2bf((v0 - mean) * inv * ln_in_g[lane] + ln_in_b[lane]);
        Xb[row * HD + 64 + lane] = f2bf((v1 - mean) * inv * ln_in_g[64 + lane] + ln_in_b[64 + lane]);
    } else if (blockIdx.x < NB_EMB + NB_PACK) {
        int idx = (blockIdx.x - NB_EMB) * 256 + t;
        if (idx < 49152) {
            int n = idx >> 7, k = idx & 127;
            Wqkv[idx] = f2bf(qkvw[k * H3X + n]);
        } else if (idx < 65536) {
            int j = idx - 49152; int n = j >> 7, k = j & 127;
            Wao[j] = f2bf(aow[k * HD + n]);
        } else if (idx < 102400) {
            int j = idx - 65536; int n = j / 288, k = j - n * 288;
            Wop1[j] = (k < FDIM) ? f2bf(op1w[k * HD + n]) : (ushort)0;
        } else if (idx < 118784) {
            int j = idx - 102400; int n = j >> 7, k = j & 127;
            Wr1[j] = f2bf(r1w[k * HD + n]);
        } else if (idx < 135168) {
            int j = idx - 118784; int n = j >> 7, k = j & 127;
            Wr2[j] = f2bf(r2w[k * HD + n]);
        }
    } else if (blockIdx.x < NB_EMB + NB_PACK + NB_CELL) {
        int r = blockIdx.x - (NB_EMB + NB_PACK);
        if (t < 128) {
            float c0 = cell[r * 3 + 0], c1 = cell[r * 3 + 1], c2 = cell[r * 3 + 2];
            float h = c0 * ce_w1[t] + c1 * ce_w1[HD + t] + c2 * ce_w1[2 * HD + t] + ce_b1[t];
            h = h / (1.f + __expf(-h));
            hs[t] = h;
        }
        __syncthreads();
        if (t < 128) {
            float acc = ce_b2[t];
#pragma unroll 8
            for (int k = 0; k < HD; k++) acc += hs[k] * ce_w2[k * HD + t];
            CF[r * HD + t] = acc;
        }
    } else {
        if (t == 0) {
            int pos = 0;
            for (int b = 0; b < BATCH; b++) { start[b] = pos; pos += num_atoms[b]; }
            start[BATCH] = pos;
        }
        __syncthreads();
        if (t < 128) {
            int s = min(start[t], NATOMS), e = min(start[t + 1], NATOMS);
            for (int j = s; j < e; j++) bidx[j] = t;
            if (t == 0) {
                int total = min(start[BATCH], NATOMS);
                for (int j = total; j < NATOMS; j++) bidx[j] = BATCH - 1;
            }
        }
        for (int rr = t; rr < BATCH * 3; rr += 256) {
            float a0 = cell[rr * 3 + 0], a1 = cell[rr * 3 + 1], a2 = cell[rr * 3 + 2];
            cmin[rr] = fminf(a0, fminf(a1, a2)) + 1e-6f;
            cmax[rr] = fmaxf(a0, fmaxf(a1, a2)) - 1e-6f;
        }
    }
}

// ---------------- QKV GEMM (MFMA) + pack Qb (scaled by 1/sqrt(32)*log2e) ------
__global__ __launch_bounds__(256) void k_qkv(const ushort* __restrict__ A,
                                             const ushort* __restrict__ Wt,
                                             const float* __restrict__ bias,
                                             ushort* __restrict__ Qb, ushort* __restrict__ Kb,
                                             ushort* __restrict__ VTb) {
    __shared__ alignas(16) ushort vt_tmp[4][128][16];
    const int t = threadIdx.x, w = t >> 6, lane = t & 63, quad = lane >> 4, lq = lane & 15;
    const int rowbase = blockIdx.x * 64 + w * 16;
    float4v acc[24];
#pragma unroll
    for (int i = 0; i < 24; i++) acc[i] = (float4v){0.f, 0.f, 0.f, 0.f};
#pragma unroll
    for (int kt = 0; kt < 4; kt++) {
        short8 af = *(const short8*)(A + (rowbase + lq) * HD + kt * 32 + quad * 8);
#pragma unroll
        for (int nt = 0; nt < 24; nt++) {
            short8 wf = *(const short8*)(Wt + (lq + 16 * nt) * HD + kt * 32 + quad * 8);
            acc[nt] = __builtin_amdgcn_mfma_f32_16x16x32_bf16(af, wf, acc[nt], 0, 0, 0);
        }
    }
#pragma unroll
    for (int nt = 0; nt < 24; nt++) {
        int col = lq + 16 * nt;
        float bb = bias[col];
#pragma unroll
        for (int r = 0; r < 4; r++) {
            float c = acc[nt][r] + bb;
            int row = rowbase + quad * 4 + r;
            if (nt < 8) {
                Qb[(((col >> 5) * NATOMS) + row) * 32 + (col & 31)] = f2bf(c * 0.25503487f);
            } else if (nt < 16) {
                int cc = col - 128;
                Kb[(((cc >> 5) * NATOMS) + row) * 32 + (cc & 31)] = f2bf(c);
            } else {
                int cc = col - 256;
                vt_tmp[w][cc][quad * 4 + r] = f2bf(c);
            }
        }
    }
#pragma unroll
    for (int pass = 0; pass < 2; pass++) {
        int cc = lane + 64 * pass;
        int hh = cc >> 5, d = cc & 31;
        uint4 a0 = *(const uint4*)&vt_tmp[w][cc][0];
        uint4 a1 = *(const uint4*)&vt_tmp[w][cc][8];
        ushort* dst = VTb + (size_t)(hh * 32 + d) * NATOMS + rowbase;
        *(uint4*)(dst) = a0;
        *(uint4*)(dst + 8) = a1;
    }
}

// ---------------- attention: 32x32x16 MFMA, S^T/O^T orientation ---------------
// Block 256thr = 4 waves: wave (qt = w&1) handles 32 queries, (kh2 = w>>1)
// handles 64-key half of each 128-key chunk. P is row-major [q][key] on BOTH
// write (S^T C-layout gives 4 consecutive keys -> ds_write_b64) and read
// (PV B-fragment = 8 consecutive keys -> ds_read_b128).  Q/K/V fragments load
// straight from global (L2).  exp2f: log2e pre-folded into Q scale.
__global__ __launch_bounds__(256) void k_attn(const ushort* __restrict__ Qb,
                                              const ushort* __restrict__ Kb,
                                              const ushort* __restrict__ VTb,
                                              ushort* __restrict__ Opart,
                                              float* __restrict__ lpart) {
    __shared__ alignas(16) ushort P_s[4][32 * 72];  // per-wave [q32][64 keys + 8 pad]
    __shared__ alignas(16) float OL[2][32 * 36];    // q-tile merge buffer
    __shared__ float LL[2][32];
    const int t = threadIdx.x, w = t >> 6, lane = t & 63;
    const int l31 = lane & 31, hi = lane >> 5;
    const int qt = w & 1, kh2 = w >> 1;
    const int h = blockIdx.y, sp = blockIdx.z;
    const int q0 = blockIdx.x * 64;
    const int qrow = q0 + qt * 32 + l31;

    short8 qf0 = *(const short8*)(Qb + (size_t)(h * NATOMS + qrow) * 32 + hi * 8);
    short8 qf1 = *(const short8*)(Qb + (size_t)(h * NATOMS + qrow) * 32 + 16 + hi * 8);
    f32x16 O = z16();
    float lp = 0.f;
    ushort* Pw = &P_s[w][0];
    const int kstart = sp * (NATOMS / SPLIT) + kh2 * 64;

    for (int ck = 0; ck < (NATOMS / SPLIT) / 128; ck++) {
        int kb = kstart + ck * 128;
#pragma unroll
        for (int kt = 0; kt < 2; kt++) {
            int kk = kb + kt * 32;
            const ushort* kp = Kb + (size_t)(h * NATOMS + kk + l31) * 32 + hi * 8;
            short8 kf0 = *(const short8*)(kp);
            short8 kf1 = *(const short8*)(kp + 16);
            f32x16 S = z16();
            S = __builtin_amdgcn_mfma_f32_32x32x16_bf16(kf0, qf0, S, 0, 0, 0);
            S = __builtin_amdgcn_mfma_f32_32x32x16_bf16(kf1, qf1, S, 0, 0, 0);
            // exp + pack 4 consecutive keys -> one b64 LDS write per c
#pragma unroll
            for (int c = 0; c < 4; c++) {
                float p0 = exp2f(S[4 * c + 0]);
                float p1 = exp2f(S[4 * c + 1]);
                float p2 = exp2f(S[4 * c + 2]);
                float p3 = exp2f(S[4 * c + 3]);
                lp += (p0 + p1) + (p2 + p3);
                uint2 u;
                u.x = (uint32_t)f2bf(p0) | ((uint32_t)f2bf(p1) << 16);
                u.y = (uint32_t)f2bf(p2) | ((uint32_t)f2bf(p3) << 16);
                *(uint2*)(&Pw[l31 * 72 + kt * 32 + c * 8 + hi * 4]) = u;
            }
            // PV: two 16-key windows
#pragma unroll
            for (int wd = 0; wd < 2; wd++) {
                int koff = kt * 32 + wd * 16;
                short8 vf = *(const short8*)(VTb + (size_t)(h * 32 + l31) * NATOMS + kb + koff + hi * 8);
                short8 pf = *(const short8*)(&Pw[l31 * 72 + koff + hi * 8]);
                O = __builtin_amdgcn_mfma_f32_32x32x16_bf16(vf, pf, O, 0, 0, 0);
            }
        }
    }
    lp += __shfl_xor(lp, 32);
    // merge the two key-half waves of each q-tile via LDS
    if (kh2 == 0) {
#pragma unroll
        for (int c = 0; c < 4; c++) {
            float4 f = {O[4 * c + 0], O[4 * c + 1], O[4 * c + 2], O[4 * c + 3]};
            *(float4*)(&OL[qt][l31 * 36 + c * 8 + hi * 4]) = f;
        }
        if (hi == 0) LL[qt][l31] = lp;
    }
    __syncthreads();
    if (kh2 == 1) {
        lp += LL[qt][l31];
#pragma unroll
        for (int c = 0; c < 4; c++) {
            float4 f = *(const float4*)(&OL[qt][l31 * 36 + c * 8 + hi * 4]);
            float o0 = O[4 * c + 0] + f.x, o1 = O[4 * c + 1] + f.y;
            float o2 = O[4 * c + 2] + f.z, o3 = O[4 * c + 3] + f.w;
            uint2 u;
            u.x = (uint32_t)f2bf(o0) | ((uint32_t)f2bf(o1) << 16);
            u.y = (uint32_t)f2bf(o2) | ((uint32_t)f2bf(o3) << 16);
            *(uint2*)(Opart + (size_t)(sp * NATOMS + qrow) * HD + h * 32 + c * 8 + hi * 4) = u;
        }
        if (hi == 0) lpart[sp * (NHEAD * NATOMS) + h * NATOMS + qrow] = lp;
    }
}

// ---------------- attn-out GEMM with fused split-combine in A-load ------------
__global__ __launch_bounds__(256) void k_ao(const ushort* __restrict__ Opart,
                                            const float* __restrict__ lpart,
                                            const ushort* __restrict__ Wt,
                                            const float* __restrict__ bias,
                                            ushort* __restrict__ X1b) {
    const int t = threadIdx.x, w = t >> 6, lane = t & 63, quad = lane >> 4, lq = lane & 15;
    const int rowbase = blockIdx.x * 64 + w * 16;
    const int arow = rowbase + lq;
    float4v acc[8];
#pragma unroll
    for (int i = 0; i < 8; i++) acc[i] = (float4v){0.f, 0.f, 0.f, 0.f};
#pragma unroll
    for (int kt = 0; kt < 4; kt++) {   // kt == head
        float l = 0.f;
#pragma unroll
        for (int s = 0; s < SPLIT; s++) l += lpart[s * (NHEAD * NATOMS) + kt * NATOMS + arow];
        float inv = 1.f / l;
        float pv[8];
#pragma unroll
        for (int j = 0; j < 8; j++) pv[j] = 0.f;
#pragma unroll
        for (int s = 0; s < SPLIT; s++) {
            short8 ov = *(const short8*)(Opart + (size_t)(s * NATOMS + arow) * HD + kt * 32 + quad * 8);
#pragma unroll
            for (int j = 0; j < 8; j++) pv[j] += b2f((ushort)ov[j]);
        }
        short8 af;
#pragma unroll
        for (int j = 0; j < 8; j++) af[j] = (short)f2bf(pv[j] * inv);
#pragma unroll
        for (int nt = 0; nt < 8; nt++) {
            short8 wf = *(const short8*)(Wt + (lq + 16 * nt) * HD + kt * 32 + quad * 8);
            acc[nt] = __builtin_amdgcn_mfma_f32_16x16x32_bf16(af, wf, acc[nt], 0, 0, 0);
        }
    }
#pragma unroll
    for (int r = 0; r < 4; r++) {
        int row = rowbase + quad * 4 + r;
#pragma unroll
        for (int nt = 0; nt < 8; nt++)
            X1b[(size_t)row * HD + lq + 16 * nt] = f2bf(acc[nt][r] + bias[lq + 16 * nt]);
    }
}

// ---------------- concat [x1 | cf[bidx] | coord] + LN(259) -> [4096][288] -----
__global__ void k_comb(const ushort* __restrict__ X1b, const float* __restrict__ CF,
                       const float* __restrict__ coord, const int* __restrict__ bidx,
                       const float* __restrict__ g, const float* __restrict__ b,
                       ushort* __restrict__ COMBb) {
    __shared__ float sc[2];
    int row = blockIdx.x, t = threadIdx.x;
    int bi = bidx[row];
    float v0 = b2f(X1b[row * HD + t]);
    float v1 = CF[bi * HD + t];
    float v2 = (t < 3) ? coord[row * 3 + t] : 0.f;
    float tot = blk_sum_128(v0 + v1 + v2, sc);
    float mean = tot * (1.f / FDIM);
    float d0 = v0 - mean, d1 = v1 - mean, d2 = (t < 3) ? (v2 - mean) : 0.f;
    float var = blk_sum_128(d0 * d0 + d1 * d1 + d2 * d2, sc) * (1.f / FDIM);
    float inv = rsqrtf(var + 1e-5f);
    COMBb[row * 288 + t] = f2bf(d0 * inv * g[t] + b[t]);
    COMBb[row * 288 + 128 + t] = f2bf(d1 * inv * g[128 + t] + b[128 + t]);
    if (t < 3) COMBb[row * 288 + 256 + t] = f2bf(d2 * inv * g[256 + t] + b[256 + t]);
    if (t >= 3 && t < 32) COMBb[row * 288 + 256 + t] = 0;
}

// ---------------- op1 GEMM (K=288) + LN + silu --------------------------------
__global__ __launch_bounds__(256) void k_op1(const ushort* __restrict__ A,
                                             const ushort* __restrict__ Wt,
                                             const float* __restrict__ bias,
                                             const float* __restrict__ lg,
                                             const float* __restrict__ lb,
                                             ushort* __restrict__ out) {
    const int t = threadIdx.x, w = t >> 6, lane = t & 63, quad = lane >> 4, lq = lane & 15;
    const int rowbase = blockIdx.x * 64 + w * 16;
    float4v acc[8];
#pragma unroll
    for (int i = 0; i < 8; i++) acc[i] = (float4v){0.f, 0.f, 0.f, 0.f};
#pragma unroll
    for (int kt = 0; kt < 9; kt++) {
        short8 af = *(const short8*)(A + (size_t)(rowbase + lq) * 288 + kt * 32 + quad * 8);
#pragma unroll
        for (int nt = 0; nt < 8; nt++) {
            short8 wf = *(const short8*)(Wt + (size_t)(lq + 16 * nt) * 288 + kt * 32 + quad * 8);
            acc[nt] = __builtin_amdgcn_mfma_f32_16x16x32_bf16(af, wf, acc[nt], 0, 0, 0);
        }
    }
#pragma unroll
    for (int r = 0; r < 4; r++) {
        float c[8], s1 = 0.f, s2 = 0.f;
#pragma unroll
        for (int nt = 0; nt < 8; nt++) {
            c[nt] = acc[nt][r] + bias[lq + 16 * nt];
            s1 += c[nt]; s2 += c[nt] * c[nt];
        }
#pragma unroll
        for (int m = 1; m < 16; m <<= 1) { s1 += __shfl_xor(s1, m); s2 += __shfl_xor(s2, m); }
        float mean = s1 * (1.f / HD);
        float var = s2 * (1.f / HD) - mean * mean;
        float inv = rsqrtf(var + 1e-5f);
        int row = rowbase + quad * 4 + r;
#pragma unroll
        for (int nt = 0; nt < 8; nt++) {
            float o = (c[nt] - mean) * inv * lg[lq + 16 * nt] + lb[lq + 16 * nt];
            o = o / (1.f + __expf(-o));
            out[(size_t)row * HD + lq + 16 * nt] = f2bf(o);
        }
    }
}

// ---------------- tail: r1 GEMM+LN+silu -> r2 GEMM+resid+LN -> w3+tanh+clamp --
__global__ __launch_bounds__(256) void k_tail(const ushort* __restrict__ Hb,
        const ushort* __restrict__ Wr1, const ushort* __restrict__ Wr2,
        const float* __restrict__ r1b, const float* __restrict__ rlg, const float* __restrict__ rlb,
        const float* __restrict__ r2b, const float* __restrict__ l2g, const float* __restrict__ l2b,
        const float* __restrict__ w3, const float* __restrict__ b3,
        const float* __restrict__ coord, const int* __restrict__ bidx,
        const float* __restrict__ cmin, const float* __restrict__ cmax,
        float* __restrict__ out) {
    __shared__ alignas(16) ushort P_s[4][16 * 136];
    const int t = threadIdx.x, w = t >> 6, lane = t & 63, quad = lane >> 4, lq = lane & 15;
    const int rowbase = blockIdx.x * 64 + w * 16;
    ushort* Pw = &P_s[w][0];
    // r1 GEMM
    float4v acc[8];
#pragma unroll
    for (int i = 0; i < 8; i++) acc[i] = (float4v){0.f, 0.f, 0.f, 0.f};
#pragma unroll
    for (int kt = 0; kt < 4; kt++) {
        short8 af = *(const short8*)(Hb + (size_t)(rowbase + lq) * HD + kt * 32 + quad * 8);
#pragma unroll
        for (int nt = 0; nt < 8; nt++) {
            short8 wf = *(const short8*)(Wr1 + (size_t)(lq + 16 * nt) * HD + kt * 32 + quad * 8);
            acc[nt] = __builtin_amdgcn_mfma_f32_16x16x32_bf16(af, wf, acc[nt], 0, 0, 0);
        }
    }
    // LN + silu -> bf16 into per-wave LDS (A-layout staging for r2)
#pragma unroll
    for (int r = 0; r < 4; r++) {
        float c[8], s1 = 0.f, s2 = 0.f;
#pragma unroll
        for (int nt = 0; nt < 8; nt++) {
            c[nt] = acc[nt][r] + r1b[lq + 16 * nt];
            s1 += c[nt]; s2 += c[nt] * c[nt];
        }
#pragma unroll
        for (int m = 1; m < 16; m <<= 1) { s1 += __shfl_xor(s1, m); s2 += __shfl_xor(s2, m); }
        float mean = s1 * (1.f / HD);
        float inv = rsqrtf(s2 * (1.f / HD) - mean * mean + 1e-5f);
#pragma unroll
        for (int nt = 0; nt < 8; nt++) {
            float o = (c[nt] - mean) * inv * rlg[lq + 16 * nt] + rlb[lq + 16 * nt];
            o = o / (1.f + __expf(-o));
            Pw[(quad * 4 + r) * 136 + lq + 16 * nt] = f2bf(o);
        }
    }
    // r2 GEMM (A from wave-local LDS; no barrier needed)
    float4v acc2[8];
#pragma unroll
    for (int i = 0; i < 8; i++) acc2[i] = (float4v){0.f, 0.f, 0.f, 0.f};
#pragma unroll
    for (int kt = 0; kt < 4; kt++) {
        short8 af = *(const short8*)(&Pw[lq * 136 + kt * 32 + quad * 8]);
#pragma unroll
        for (int nt = 0; nt < 8; nt++) {
            short8 wf = *(const short8*)(Wr2 + (size_t)(lq + 16 * nt) * HD + kt * 32 + quad * 8);
            acc2[nt] = __builtin_amdgcn_mfma_f32_16x16x32_bf16(af, wf, acc2[nt], 0, 0, 0);
        }
    }
    // + r2 bias + residual(Hb) -> LN -> w3 matvec -> tanh*0.01 -> clamp -> out
#pragma unroll
    for (int r = 0; r < 4; r++) {
        int row = rowbase + quad * 4 + r;
        float c[8], s1 = 0.f, s2 = 0.f;
#pragma unroll
        for (int nt = 0; nt < 8; nt++) {
            c[nt] = acc2[nt][r] + r2b[lq + 16 * nt] + b2f(Hb[(size_t)row * HD + lq + 16 * nt]);
            s1 += c[nt]; s2 += c[nt] * c[nt];
        }
#pragma unroll
        for (int m = 1; m < 16; m <<= 1) { s1 += __shfl_xor(s1, m); s2 += __shfl_xor(s2, m); }
        float mean = s1 * (1.f / HD);
        float inv = rsqrtf(s2 * (1.f / HD) - mean * mean + 1e-5f);
        float t0 = 0.f, t1 = 0.f, t2 = 0.f;
#pragma unroll
        for (int nt = 0; nt < 8; nt++) {
            int col = lq + 16 * nt;
            float h2 = (c[nt] - mean) * inv * l2g[col] + l2b[col];
            t0 += h2 * w3[col * 3 + 0];
            t1 += h2 * w3[col * 3 + 1];
            t2 += h2 * w3[col * 3 + 2];
        }
#pragma unroll
        for (int m = 1; m < 16; m <<= 1) {
            t0 += __shfl_xor(t0, m); t1 += __shfl_xor(t1, m); t2 += __shfl_xor(t2, m);
        }
        if (lq < 3) {
            float sv = (lq == 0) ? t0 : ((lq == 1) ? t1 : t2);
            float off = tanhf(sv + b3[lq]) * 0.01f;
            int bi = bidx[row];
            float pert = coord[row * 3 + lq] + off;
            pert = fminf(fmaxf(pert, cmin[bi * 3 + lq]), cmax[bi * 3 + lq]);
            out[row * 3 + lq] = pert;
        }
    }
}

extern "C" void kernel_launch(void* const* d_in, const int* in_sizes, int n_in,
                              void* d_out, int out_size, void* d_ws, size_t ws_size,
                              hipStream_t stream) {
    const int* num_atoms = (const int*)d_in[0];
    const int* elems = (const int*)d_in[1];
    const float* cell = (const float*)d_in[2];
    const float* coord = (const float*)d_in[3];
    const float* emb = (const float*)d_in[4];
    const float* ln_in_g = (const float*)d_in[5];
    const float* ln_in_b = (const float*)d_in[6];
    const float* attn_in_w = (const float*)d_in[7];
    const float* attn_in_b = (const float*)d_in[8];
    const float* attn_out_w = (const float*)d_in[9];
    const float* attn_out_b = (const float*)d_in[10];
    const float* ce_w1 = (const float*)d_in[11];
    const float* ce_b1 = (const float*)d_in[12];
    const float* ce_w2 = (const float*)d_in[13];
    const float* ce_b2 = (const float*)d_in[14];
    const float* ln_feat_g = (const float*)d_in[15];
    const float* ln_feat_b = (const float*)d_in[16];
    const float* op_w1 = (const float*)d_in[17];
    const float* op_b1 = (const float*)d_in[18];
    const float* op_ln1_g = (const float*)d_in[19];
    const float* op_ln1_b = (const float*)d_in[20];
    const float* res_w1 = (const float*)d_in[21];
    const float* res_b1 = (const float*)d_in[22];
    const float* res_ln_g = (const float*)d_in[23];
    const float* res_ln_b = (const float*)d_in[24];
    const float* res_w2 = (const float*)d_in[25];
    const float* res_b2 = (const float*)d_in[26];
    const float* op_ln2_g = (const float*)d_in[27];
    const float* op_ln2_b = (const float*)d_in[28];
    const float* op_w3 = (const float*)d_in[29];
    const float* op_b3 = (const float*)d_in[30];

    // workspace (~8.6 MB peak, lifetimes tracked):
    char* ws = (char*)d_ws;
    const size_t MB = 1u << 20;
    ushort* Xb = (ushort*)(ws);                       // [0,1M)  dead after k_qkv
    ushort* X1b = (ushort*)(ws);                      // reuse [0,1M)
    ushort* Qb = (ushort*)(ws + 1 * MB);
    ushort* Kb = (ushort*)(ws + 2 * MB);
    ushort* VTb = (ushort*)(ws + 3 * MB);
    ushort* Opart = (ushort*)(ws + 4 * MB);           // [4M,8M)  dead after k_ao
    ushort* COMBb = (ushort*)(ws + 4 * MB);           // reuse [4M,6.25M)
    ushort* Hb = (ushort*)(ws + 6 * MB + (512u << 10)); // [6.5M,7.5M)
    float* lpart = (float*)(ws + 8 * MB);             // 256 KB
    int* bidx = (int*)(ws + 8 * MB + (256u << 10));
    float* cmin = (float*)(ws + 8 * MB + (272u << 10));
    float* cmax = (float*)(ws + 8 * MB + (274u << 10));
    float* CF = (float*)(ws + 8 * MB + (276u << 10));
    ushort* Wqkv = (ushort*)(ws + 8 * MB + (340u << 10));
    ushort* Wao = (ushort*)(ws + 8 * MB + (436u << 10));
    ushort* Wop1 = (ushort*)(ws + 8 * MB + (468u << 10));
    ushort* Wr1 = (ushort*)(ws + 8 * MB + (540u << 10));
    ushort* Wr2 = (ushort*)(ws + 8 * MB + (572u << 10));

    k_setup<<<NB_EMB + NB_PACK + NB_CELL + 1, 256, 0, stream>>>(
        num_atoms, cell, elems, emb, ln_in_g, ln_in_b,
        attn_in_w, attn_out_w, op_w1, res_w1, res_w2,
        ce_w1, ce_b1, ce_w2, ce_b2,
        bidx, cmin, cmax, Xb, Wqkv, Wao, Wop1, Wr1, Wr2, CF);
    k_qkv<<<64, 256, 0, stream>>>(Xb, Wqkv, attn_in_b, Qb, Kb, VTb);
    k_attn<<<dim3(NATOMS / 64, NHEAD, SPLIT), 256, 0, stream>>>(Qb, Kb, VTb, Opart, lpart);
    k_ao<<<64, 256, 0, stream>>>(Opart, lpart, Wao, attn_out_b, X1b);
    k_comb<<<NATOMS, 128, 0, stream>>>(X1b, CF, coord, bidx, ln_feat_g, ln_feat_b, COMBb);
    k_op1<<<64, 256, 0, stream>>>(COMBb, Wop1, op_b1, op_ln1_g, op_ln1_b, Hb);
    k_tail<<<64, 256, 0, stream>>>(Hb, Wr1, Wr2, res_b1, res_ln_g, res_ln_b,
                                   res_b2, op_ln2_g, op_ln2_b, op_w3, op_b3,
                                   coord, bidx, cmin, cmax, (float*)d_out);
}

// Round 7
// 179.374 us; speedup vs baseline: 3.0730x; 1.1978x over previous
//
#include <hip/hip_runtime.h>
#include <hip/hip_bf16.h>
#include <math.h>
#include <stdint.h>

#define NATOMS 4096
#define HD     128
#define NHEAD  4
#define DHEAD  32
#define FDIM   259
#define BATCH  128
#define H3X    384
#define SPLIT  4

typedef __attribute__((ext_vector_type(8))) short short8;
typedef __attribute__((ext_vector_type(4))) float float4v;
typedef __attribute__((ext_vector_type(16))) float f32x16;

__device__ __forceinline__ ushort f2bf(float f) {
    uint32_t u = __float_as_uint(f);
    return (ushort)((u + 0x7fffu + ((u >> 16) & 1u)) >> 16);
}
__device__ __forceinline__ float b2f(ushort u) {
    return __uint_as_float(((uint32_t)u) << 16);
}
__device__ __forceinline__ f32x16 z16() {
    f32x16 v;
#pragma unroll
    for (int i = 0; i < 16; i++) v[i] = 0.f;
    return v;
}

// ---------------- setup: weight pack | cell MLP | prep ------------------------
#define NB_PACK 528
#define NB_CELL 128
__global__ __launch_bounds__(256) void k_setup(
        const int* __restrict__ num_atoms, const float* __restrict__ cell,
        const float* __restrict__ qkvw, const float* __restrict__ aow,
        const float* __restrict__ op1w, const float* __restrict__ r1w,
        const float* __restrict__ r2w,
        const float* __restrict__ ce_w1, const float* __restrict__ ce_b1,
        const float* __restrict__ ce_w2, const float* __restrict__ ce_b2,
        int* __restrict__ bidx, float* __restrict__ cmin, float* __restrict__ cmax,
        ushort* __restrict__ Wqkv, ushort* __restrict__ Wao,
        ushort* __restrict__ Wop1, ushort* __restrict__ Wr1, ushort* __restrict__ Wr2,
        float* __restrict__ CF) {
    __shared__ float hs[HD];
    __shared__ int start[BATCH + 1];
    const int t = threadIdx.x;
    if (blockIdx.x < NB_PACK) {
        int idx = blockIdx.x * 256 + t;
        if (idx < 49152) {
            int n = idx >> 7, k = idx & 127;
            Wqkv[idx] = f2bf(qkvw[k * H3X + n]);
        } else if (idx < 65536) {
            int j = idx - 49152; int n = j >> 7, k = j & 127;
            Wao[j] = f2bf(aow[k * HD + n]);
        } else if (idx < 102400) {
            int j = idx - 65536; int n = j / 288, k = j - n * 288;
            Wop1[j] = (k < FDIM) ? f2bf(op1w[k * HD + n]) : (ushort)0;
        } else if (idx < 118784) {
            int j = idx - 102400; int n = j >> 7, k = j & 127;
            Wr1[j] = f2bf(r1w[k * HD + n]);
        } else if (idx < 135168) {
            int j = idx - 118784; int n = j >> 7, k = j & 127;
            Wr2[j] = f2bf(r2w[k * HD + n]);
        }
    } else if (blockIdx.x < NB_PACK + NB_CELL) {
        int r = blockIdx.x - NB_PACK;
        if (t < 128) {
            float c0 = cell[r * 3 + 0], c1 = cell[r * 3 + 1], c2 = cell[r * 3 + 2];
            float h = c0 * ce_w1[t] + c1 * ce_w1[HD + t] + c2 * ce_w1[2 * HD + t] + ce_b1[t];
            h = h / (1.f + __expf(-h));
            hs[t] = h;
        }
        __syncthreads();
        if (t < 128) {
            float acc = ce_b2[t];
#pragma unroll 8
            for (int k = 0; k < HD; k++) acc += hs[k] * ce_w2[k * HD + t];
            CF[r * HD + t] = acc;
        }
    } else {
        if (t == 0) {
            int pos = 0;
            for (int b = 0; b < BATCH; b++) { start[b] = pos; pos += num_atoms[b]; }
            start[BATCH] = pos;
        }
        __syncthreads();
        if (t < 128) {
            int s = min(start[t], NATOMS), e = min(start[t + 1], NATOMS);
            for (int j = s; j < e; j++) bidx[j] = t;
            if (t == 0) {
                int total = min(start[BATCH], NATOMS);
                for (int j = total; j < NATOMS; j++) bidx[j] = BATCH - 1;
            }
        }
        for (int rr = t; rr < BATCH * 3; rr += 256) {
            float a0 = cell[rr * 3 + 0], a1 = cell[rr * 3 + 1], a2 = cell[rr * 3 + 2];
            cmin[rr] = fminf(a0, fminf(a1, a2)) + 1e-6f;
            cmax[rr] = fmaxf(a0, fmaxf(a1, a2)) - 1e-6f;
        }
    }
}

// ---------------- QKV: fused embed+LN prologue, MFMA GEMM, packed outputs -----
// grid 256: block = 16 atom rows, 4 waves x 6 col-tiles (96 cols each).
// VTb2 layout: [h][key64-tile][d(32)][key-in-tile(64)] bf16.
__global__ __launch_bounds__(256) void k_qkv(const int* __restrict__ elems,
                                             const float* __restrict__ emb,
                                             const float* __restrict__ lg,
                                             const float* __restrict__ lb,
                                             const ushort* __restrict__ Wt,
                                             const float* __restrict__ bias,
                                             ushort* __restrict__ Qb, ushort* __restrict__ Kb,
                                             ushort* __restrict__ VTb2) {
    __shared__ alignas(16) ushort Af[4][64][8];   // A frags [kt][lane][8]
    __shared__ alignas(16) ushort vt[128][16];    // V^T staging: [(h,d)][atom-in-block]
    const int t = threadIdx.x, w = t >> 6, lane = t & 63, quad = lane >> 4, lq = lane & 15;
    const int rb = blockIdx.x * 16;
    // embed + LN: thread t -> row t>>4, cols (t&15)*8..+7
    {
        int row = t >> 4, seg = t & 15;
        int e = elems[rb + row];
        const float* ep = emb + (size_t)e * HD + seg * 8;
        float v[8]; float s = 0.f, ss = 0.f;
#pragma unroll
        for (int j = 0; j < 8; j++) { v[j] = ep[j]; s += v[j]; ss += v[j] * v[j]; }
#pragma unroll
        for (int m = 1; m < 16; m <<= 1) { s += __shfl_xor(s, m); ss += __shfl_xor(ss, m); }
        float mean = s * (1.f / HD);
        float inv = rsqrtf(ss * (1.f / HD) - mean * mean + 1e-5f);
        ushort o[8];
#pragma unroll
        for (int j = 0; j < 8; j++)
            o[j] = f2bf((v[j] - mean) * inv * lg[seg * 8 + j] + lb[seg * 8 + j]);
        *(uint4*)&Af[seg >> 2][(seg & 3) * 16 + row][0] = *(uint4*)o;
    }
    __syncthreads();
    float4v acc[6];
#pragma unroll
    for (int i = 0; i < 6; i++) acc[i] = (float4v){0.f, 0.f, 0.f, 0.f};
#pragma unroll
    for (int kt = 0; kt < 4; kt++) {
        short8 af = *(const short8*)&Af[kt][lane][0];
#pragma unroll
        for (int i = 0; i < 6; i++) {
            int nt = w * 6 + i;
            short8 wf = *(const short8*)(Wt + (size_t)(lq + 16 * nt) * HD + kt * 32 + quad * 8);
            acc[i] = __builtin_amdgcn_mfma_f32_16x16x32_bf16(af, wf, acc[i], 0, 0, 0);
        }
    }
#pragma unroll
    for (int i = 0; i < 6; i++) {
        int col = lq + 16 * (w * 6 + i);
        float bb = bias[col];
#pragma unroll
        for (int r = 0; r < 4; r++) {
            float c = acc[i][r] + bb;
            int rowin = quad * 4 + r;
            int row = rb + rowin;
            if (col < 128) {
                Qb[(size_t)(((col >> 5) * NATOMS) + row) * 32 + (col & 31)] = f2bf(c * 0.25503483f);
            } else if (col < 256) {
                int cc = col - 128;
                Kb[(size_t)(((cc >> 5) * NATOMS) + row) * 32 + (cc & 31)] = f2bf(c);
            } else {
                vt[col - 256][rowin] = f2bf(c);
            }
        }
    }
    __syncthreads();
    if (t < 128) {
        int hh = t >> 5, d = t & 31;
        uint4 a0 = *(const uint4*)&vt[t][0];
        uint4 a1 = *(const uint4*)&vt[t][8];
        ushort* dst = VTb2 + ((size_t)(hh * 64 + (rb >> 6)) * 32 + d) * 64 + (rb & 63);
        *(uint4*)(dst) = a0;
        *(uint4*)(dst + 8) = a1;
    }
}

// ---------------- attention: 32x32x16, S^T/O^T, split-K -----------------------
__global__ __launch_bounds__(256) void k_attn(const ushort* __restrict__ Qb,
                                              const ushort* __restrict__ Kb,
                                              const ushort* __restrict__ VTb2,
                                              ushort* __restrict__ Opart,
                                              float* __restrict__ lpart) {
    __shared__ alignas(16) ushort P_s[4][32 * 72];
    __shared__ alignas(16) float OL[2][32 * 36];
    __shared__ float LL[2][32];
    const int t = threadIdx.x, w = t >> 6, lane = t & 63;
    const int l31 = lane & 31, hi = lane >> 5;
    const int qt = w & 1, kh2 = w >> 1;
    const int h = blockIdx.y, sp = blockIdx.z;
    const int q0 = blockIdx.x * 64;
    const int qrow = q0 + qt * 32 + l31;

    short8 qf0 = *(const short8*)(Qb + (size_t)(h * NATOMS + qrow) * 32 + hi * 8);
    short8 qf1 = *(const short8*)(Qb + (size_t)(h * NATOMS + qrow) * 32 + 16 + hi * 8);
    f32x16 O = z16();
    float lp = 0.f;
    ushort* Pw = &P_s[w][0];
    const int kstart = sp * (NATOMS / SPLIT) + kh2 * 64;

    for (int ck = 0; ck < (NATOMS / SPLIT) / 128; ck++) {
        int kb = kstart + ck * 128;
        const ushort* vbase = VTb2 + ((size_t)(h * 64 + (kb >> 6)) * 32 + l31) * 64;
#pragma unroll
        for (int kt = 0; kt < 2; kt++) {
            int kk = kb + kt * 32;
            const ushort* kp = Kb + (size_t)(h * NATOMS + kk + l31) * 32 + hi * 8;
            short8 kf0 = *(const short8*)(kp);
            short8 kf1 = *(const short8*)(kp + 16);
            f32x16 S = z16();
            S = __builtin_amdgcn_mfma_f32_32x32x16_bf16(kf0, qf0, S, 0, 0, 0);
            S = __builtin_amdgcn_mfma_f32_32x32x16_bf16(kf1, qf1, S, 0, 0, 0);
#pragma unroll
            for (int c = 0; c < 4; c++) {
                float p0 = exp2f(S[4 * c + 0]);
                float p1 = exp2f(S[4 * c + 1]);
                float p2 = exp2f(S[4 * c + 2]);
                float p3 = exp2f(S[4 * c + 3]);
                lp += (p0 + p1) + (p2 + p3);
                uint32_t u0 = __float_as_uint(p0) + 0x8000u;
                uint32_t u1 = __float_as_uint(p1) + 0x8000u;
                uint32_t u2 = __float_as_uint(p2) + 0x8000u;
                uint32_t u3 = __float_as_uint(p3) + 0x8000u;
                uint2 u;
                u.x = __builtin_amdgcn_perm(u1, u0, 0x07060302u);
                u.y = __builtin_amdgcn_perm(u3, u2, 0x07060302u);
                *(uint2*)(&Pw[l31 * 72 + kt * 32 + c * 8 + hi * 4]) = u;
            }
#pragma unroll
            for (int wd = 0; wd < 2; wd++) {
                int koff = kt * 32 + wd * 16;
                short8 vf = *(const short8*)(vbase + koff + hi * 8);
                short8 pf = *(const short8*)(&Pw[l31 * 72 + koff + hi * 8]);
                O = __builtin_amdgcn_mfma_f32_32x32x16_bf16(vf, pf, O, 0, 0, 0);
            }
        }
    }
    lp += __shfl_xor(lp, 32);
    if (kh2 == 0) {
#pragma unroll
        for (int c = 0; c < 4; c++) {
            float4 f = {O[4 * c + 0], O[4 * c + 1], O[4 * c + 2], O[4 * c + 3]};
            *(float4*)(&OL[qt][l31 * 36 + c * 8 + hi * 4]) = f;
        }
        if (hi == 0) LL[qt][l31] = lp;
    }
    __syncthreads();
    if (kh2 == 1) {
        lp += LL[qt][l31];
#pragma unroll
        for (int c = 0; c < 4; c++) {
            float4 f = *(const float4*)(&OL[qt][l31 * 36 + c * 8 + hi * 4]);
            float o0 = O[4 * c + 0] + f.x, o1 = O[4 * c + 1] + f.y;
            float o2 = O[4 * c + 2] + f.z, o3 = O[4 * c + 3] + f.w;
            uint2 u;
            u.x = (uint32_t)f2bf(o0) | ((uint32_t)f2bf(o1) << 16);
            u.y = (uint32_t)f2bf(o2) | ((uint32_t)f2bf(o3) << 16);
            *(uint2*)(Opart + (size_t)(sp * NATOMS + qrow) * HD + h * 32 + c * 8 + hi * 4) = u;
        }
        if (hi == 0) lpart[sp * (NHEAD * NATOMS) + h * NATOMS + qrow] = lp;
    }
}

// ---------------- back: ao + comb(LN259) + op1 + r1 + r2 + LN + w3 + clamp ----
// grid 256: block = 16 rows; 4 waves column-split (2 col-tiles of 16 each).
__global__ __launch_bounds__(256) void k_back(
        const ushort* __restrict__ Opart, const float* __restrict__ lpart,
        const ushort* __restrict__ Wao, const float* __restrict__ aob,
        const float* __restrict__ CF, const float* __restrict__ coord,
        const int* __restrict__ bidx,
        const float* __restrict__ fg, const float* __restrict__ fb,
        const ushort* __restrict__ Wop1, const float* __restrict__ op1b,
        const float* __restrict__ l1g, const float* __restrict__ l1b,
        const ushort* __restrict__ Wr1, const float* __restrict__ r1b,
        const float* __restrict__ rlg, const float* __restrict__ rlb,
        const ushort* __restrict__ Wr2, const float* __restrict__ r2b,
        const float* __restrict__ l2g, const float* __restrict__ l2b,
        const float* __restrict__ w3, const float* __restrict__ b3,
        const float* __restrict__ cmin, const float* __restrict__ cmax,
        float* __restrict__ out) {
    __shared__ alignas(16) ushort AF1[9][64][8];   // COMB frags (K=288)
    __shared__ alignas(16) ushort AF2[4][64][8];   // H frags (also residual)
    __shared__ alignas(16) ushort AF3[4][64][8];   // R frags
    __shared__ float RED[4][16][4];
    __shared__ float REDC[16][2];
    __shared__ float COORDS[16][3];
    const int t = threadIdx.x, w = t >> 6, lane = t & 63, quad = lane >> 4, lq = lane & 15;
    const int rb = blockIdx.x * 16;
    const int col0 = lq + 32 * w, col1 = col0 + 16;

    // ---- stage A: split-combine + attn-out GEMM ----
    const int arow = rb + lq;
    float4v a0 = {0.f,0.f,0.f,0.f}, a1 = {0.f,0.f,0.f,0.f};
#pragma unroll
    for (int h = 0; h < 4; h++) {
        float l = 0.f;
#pragma unroll
        for (int s = 0; s < SPLIT; s++) l += lpart[s * (NHEAD * NATOMS) + h * NATOMS + arow];
        float inv = 1.f / l;
        float pv[8];
#pragma unroll
        for (int j = 0; j < 8; j++) pv[j] = 0.f;
#pragma unroll
        for (int s = 0; s < SPLIT; s++) {
            short8 ov = *(const short8*)(Opart + (size_t)(s * NATOMS + arow) * HD + h * 32 + quad * 8);
#pragma unroll
            for (int j = 0; j < 8; j++) pv[j] += b2f((ushort)ov[j]);
        }
        short8 af;
#pragma unroll
        for (int j = 0; j < 8; j++) af[j] = (short)f2bf(pv[j] * inv);
        short8 w0 = *(const short8*)(Wao + (size_t)col0 * HD + h * 32 + quad * 8);
        short8 w1 = *(const short8*)(Wao + (size_t)col1 * HD + h * 32 + quad * 8);
        a0 = __builtin_amdgcn_mfma_f32_16x16x32_bf16(af, w0, a0, 0, 0, 0);
        a1 = __builtin_amdgcn_mfma_f32_16x16x32_bf16(af, w1, a1, 0, 0, 0);
    }
    float x1[2][4];
#pragma unroll
    for (int r = 0; r < 4; r++) { x1[0][r] = a0[r] + aob[col0]; x1[1][r] = a1[r] + aob[col1]; }

    // ---- stage B: comb LN(259) -> AF1 ----
    float cfv[2][4];
#pragma unroll
    for (int r = 0; r < 4; r++) {
        int bi = bidx[rb + quad * 4 + r];
        cfv[0][r] = CF[bi * HD + col0];
        cfv[1][r] = CF[bi * HD + col1];
    }
#pragma unroll
    for (int r = 0; r < 4; r++) {
        float s1 = x1[0][r] + x1[1][r] + cfv[0][r] + cfv[1][r];
        float s2 = x1[0][r]*x1[0][r] + x1[1][r]*x1[1][r] + cfv[0][r]*cfv[0][r] + cfv[1][r]*cfv[1][r];
#pragma unroll
        for (int m = 1; m < 16; m <<= 1) { s1 += __shfl_xor(s1, m); s2 += __shfl_xor(s2, m); }
        if (lq == 0) { RED[w][quad * 4 + r][0] = s1; RED[w][quad * 4 + r][1] = s2; }
    }
    if (t < 16) {
        float c0 = coord[(rb + t) * 3 + 0], c1 = coord[(rb + t) * 3 + 1], c2 = coord[(rb + t) * 3 + 2];
        COORDS[t][0] = c0; COORDS[t][1] = c1; COORDS[t][2] = c2;
        REDC[t][0] = c0 + c1 + c2; REDC[t][1] = c0*c0 + c1*c1 + c2*c2;
    }
    if (t < 64) { uint4 z = {0,0,0,0}; *(uint4*)&AF1[8][t][0] = z; }
    __syncthreads();
    {
#pragma unroll
        for (int r = 0; r < 4; r++) {
            int ri = quad * 4 + r;
            float s1 = RED[0][ri][0] + RED[1][ri][0] + RED[2][ri][0] + RED[3][ri][0] + REDC[ri][0];
            float s2 = RED[0][ri][1] + RED[1][ri][1] + RED[2][ri][1] + RED[3][ri][1] + REDC[ri][1];
            float mn = s1 * (1.f / FDIM);
            float iv = rsqrtf(s2 * (1.f / FDIM) - mn * mn + 1e-5f);
#pragma unroll
            for (int i = 0; i < 2; i++) {
                int c = i ? col1 : col0;
                float vx = ((i ? x1[1][r] : x1[0][r]) - mn) * iv * fg[c] + fb[c];
                float vc = ((i ? cfv[1][r] : cfv[0][r]) - mn) * iv * fg[c + 128] + fb[c + 128];
                AF1[c >> 5][((c >> 3) & 3) * 16 + ri][c & 7] = f2bf(vx);
                int c2 = c + 128;
                AF1[c2 >> 5][((c2 >> 3) & 3) * 16 + ri][c2 & 7] = f2bf(vc);
            }
        }
        if (t < 16) {
            float s1 = RED[0][t][0] + RED[1][t][0] + RED[2][t][0] + RED[3][t][0] + REDC[t][0];
            float s2 = RED[0][t][1] + RED[1][t][1] + RED[2][t][1] + RED[3][t][1] + REDC[t][1];
            float mn = s1 * (1.f / FDIM);
            float iv = rsqrtf(s2 * (1.f / FDIM) - mn * mn + 1e-5f);
#pragma unroll
            for (int c = 0; c < 3; c++)
                AF1[8][t][c] = f2bf((COORDS[t][c] - mn) * iv * fg[256 + c] + fb[256 + c]);
        }
    }
    __syncthreads();

    // ---- stage C: op1 (K=288) + LN + silu -> AF2 ----
    float4v c0v = {0.f,0.f,0.f,0.f}, c1v = {0.f,0.f,0.f,0.f};
#pragma unroll
    for (int kt = 0; kt < 9; kt++) {
        short8 af = *(const short8*)&AF1[kt][lane][0];
        short8 w0 = *(const short8*)(Wop1 + (size_t)col0 * 288 + kt * 32 + quad * 8);
        short8 w1 = *(const short8*)(Wop1 + (size_t)col1 * 288 + kt * 32 + quad * 8);
        c0v = __builtin_amdgcn_mfma_f32_16x16x32_bf16(af, w0, c0v, 0, 0, 0);
        c1v = __builtin_amdgcn_mfma_f32_16x16x32_bf16(af, w1, c1v, 0, 0, 0);
    }
    float h0[4], h1[4];
#pragma unroll
    for (int r = 0; r < 4; r++) {
        h0[r] = c0v[r] + op1b[col0]; h1[r] = c1v[r] + op1b[col1];
        float s1 = h0[r] + h1[r], s2 = h0[r]*h0[r] + h1[r]*h1[r];
#pragma unroll
        for (int m = 1; m < 16; m <<= 1) { s1 += __shfl_xor(s1, m); s2 += __shfl_xor(s2, m); }
        if (lq == 0) { RED[w][quad * 4 + r][0] = s1; RED[w][quad * 4 + r][1] = s2; }
    }
    __syncthreads();
#pragma unroll
    for (int r = 0; r < 4; r++) {
        int ri = quad * 4 + r;
        float s1 = RED[0][ri][0] + RED[1][ri][0] + RED[2][ri][0] + RED[3][ri][0];
        float s2 = RED[0][ri][1] + RED[1][ri][1] + RED[2][ri][1] + RED[3][ri][1];
        float mn = s1 * (1.f / HD);
        float iv = rsqrtf(s2 * (1.f / HD) - mn * mn + 1e-5f);
#pragma unroll
        for (int i = 0; i < 2; i++) {
            int c = i ? col1 : col0;
            float o = ((i ? h1[r] : h0[r]) - mn) * iv * l1g[c] + l1b[c];
            o = o / (1.f + __expf(-o));
            AF2[c >> 5][((c >> 3) & 3) * 16 + ri][c & 7] = f2bf(o);
        }
    }
    __syncthreads();

    // ---- stage D: r1 + LN + silu -> AF3 ----
    float4v d0v = {0.f,0.f,0.f,0.f}, d1v = {0.f,0.f,0.f,0.f};
#pragma unroll
    for (int kt = 0; kt < 4; kt++) {
        short8 af = *(const short8*)&AF2[kt][lane][0];
        short8 w0 = *(const short8*)(Wr1 + (size_t)col0 * HD + kt * 32 + quad * 8);
        short8 w1 = *(const short8*)(Wr1 + (size_t)col1 * HD + kt * 32 + quad * 8);
        d0v = __builtin_amdgcn_mfma_f32_16x16x32_bf16(af, w0, d0v, 0, 0, 0);
        d1v = __builtin_amdgcn_mfma_f32_16x16x32_bf16(af, w1, d1v, 0, 0, 0);
    }
    float e0[4], e1[4];
#pragma unroll
    for (int r = 0; r < 4; r++) {
        e0[r] = d0v[r] + r1b[col0]; e1[r] = d1v[r] + r1b[col1];
        float s1 = e0[r] + e1[r], s2 = e0[r]*e0[r] + e1[r]*e1[r];
#pragma unroll
        for (int m = 1; m < 16; m <<= 1) { s1 += __shfl_xor(s1, m); s2 += __shfl_xor(s2, m); }
        if (lq == 0) { RED[w][quad * 4 + r][0] = s1; RED[w][quad * 4 + r][1] = s2; }
    }
    __syncthreads();
#pragma unroll
    for (int r = 0; r < 4; r++) {
        int ri = quad * 4 + r;
        float s1 = RED[0][ri][0] + RED[1][ri][0] + RED[2][ri][0] + RED[3][ri][0];
        float s2 = RED[0][ri][1] + RED[1][ri][1] + RED[2][ri][1] + RED[3][ri][1];
        float mn = s1 * (1.f / HD);
        float iv = rsqrtf(s2 * (1.f / HD) - mn * mn + 1e-5f);
#pragma unroll
        for (int i = 0; i < 2; i++) {
            int c = i ? col1 : col0;
            float o = ((i ? e1[r] : e0[r]) - mn) * iv * rlg[c] + rlb[c];
            o = o / (1.f + __expf(-o));
            AF3[c >> 5][((c >> 3) & 3) * 16 + ri][c & 7] = f2bf(o);
        }
    }
    __syncthreads();

    // ---- stage E: r2 + resid + LN + w3 + tanh + clamp ----
    float4v f0v = {0.f,0.f,0.f,0.f}, f1v = {0.f,0.f,0.f,0.f};
#pragma unroll
    for (int kt = 0; kt < 4; kt++) {
        short8 af = *(const short8*)&AF3[kt][lane][0];
        short8 w0 = *(const short8*)(Wr2 + (size_t)col0 * HD + kt * 32 + quad * 8);
        short8 w1 = *(const short8*)(Wr2 + (size_t)col1 * HD + kt * 32 + quad * 8);
        f0v = __builtin_amdgcn_mfma_f32_16x16x32_bf16(af, w0, f0v, 0, 0, 0);
        f1v = __builtin_amdgcn_mfma_f32_16x16x32_bf16(af, w1, f1v, 0, 0, 0);
    }
    float g0r[4], g1r[4];
#pragma unroll
    for (int r = 0; r < 4; r++) {
        int ri = quad * 4 + r;
        float rs0 = b2f(AF2[col0 >> 5][((col0 >> 3) & 3) * 16 + ri][col0 & 7]);
        float rs1 = b2f(AF2[col1 >> 5][((col1 >> 3) & 3) * 16 + ri][col1 & 7]);
        g0r[r] = f0v[r] + r2b[col0] + rs0;
        g1r[r] = f1v[r] + r2b[col1] + rs1;
        float s1 = g0r[r] + g1r[r], s2 = g0r[r]*g0r[r] + g1r[r]*g1r[r];
#pragma unroll
        for (int m = 1; m < 16; m <<= 1) { s1 += __shfl_xor(s1, m); s2 += __shfl_xor(s2, m); }
        if (lq == 0) { RED[w][ri][0] = s1; RED[w][ri][1] = s2; }
    }
    __syncthreads();
    float tp[4][3];
#pragma unroll
    for (int r = 0; r < 4; r++) {
        int ri = quad * 4 + r;
        float s1 = RED[0][ri][0] + RED[1][ri][0] + RED[2][ri][0] + RED[3][ri][0];
        float s2 = RED[0][ri][1] + RED[1][ri][1] + RED[2][ri][1] + RED[3][ri][1];
        float mn = s1 * (1.f / HD);
        float iv = rsqrtf(s2 * (1.f / HD) - mn * mn + 1e-5f);
        float h20 = (g0r[r] - mn) * iv * l2g[col0] + l2b[col0];
        float h21 = (g1r[r] - mn) * iv * l2g[col1] + l2b[col1];
#pragma unroll
        for (int c = 0; c < 3; c++) {
            float v = h20 * w3[col0 * 3 + c] + h21 * w3[col1 * 3 + c];
#pragma unroll
            for (int m = 1; m < 16; m <<= 1) v += __shfl_xor(v, m);
            tp[r][c] = v;
        }
    }
    __syncthreads();
    if (lq == 0) {
#pragma unroll
        for (int r = 0; r < 4; r++) {
            RED[w][quad * 4 + r][0] = tp[r][0];
            RED[w][quad * 4 + r][1] = tp[r][1];
            RED[w][quad * 4 + r][2] = tp[r][2];
        }
    }
    __syncthreads();
    if (t < 16) {
        int bi = bidx[rb + t];
#pragma unroll
        for (int c = 0; c < 3; c++) {
            float sv = RED[0][t][c] + RED[1][t][c] + RED[2][t][c] + RED[3][t][c];
            float off = tanhf(sv + b3[c]) * 0.01f;
            float pert = COORDS[t][c] + off;
            pert = fminf(fmaxf(pert, cmin[bi * 3 + c]), cmax[bi * 3 + c]);
            out[(rb + t) * 3 + c] = pert;
        }
    }
}

extern "C" void kernel_launch(void* const* d_in, const int* in_sizes, int n_in,
                              void* d_out, int out_size, void* d_ws, size_t ws_size,
                              hipStream_t stream) {
    const int* num_atoms = (const int*)d_in[0];
    const int* elems = (const int*)d_in[1];
    const float* cell = (const float*)d_in[2];
    const float* coord = (const float*)d_in[3];
    const float* emb = (const float*)d_in[4];
    const float* ln_in_g = (const float*)d_in[5];
    const float* ln_in_b = (const float*)d_in[6];
    const float* attn_in_w = (const float*)d_in[7];
    const float* attn_in_b = (const float*)d_in[8];
    const float* attn_out_w = (const float*)d_in[9];
    const float* attn_out_b = (const float*)d_in[10];
    const float* ce_w1 = (const float*)d_in[11];
    const float* ce_b1 = (const float*)d_in[12];
    const float* ce_w2 = (const float*)d_in[13];
    const float* ce_b2 = (const float*)d_in[14];
    const float* ln_feat_g = (const float*)d_in[15];
    const float* ln_feat_b = (const float*)d_in[16];
    const float* op_w1 = (const float*)d_in[17];
    const float* op_b1 = (const float*)d_in[18];
    const float* op_ln1_g = (const float*)d_in[19];
    const float* op_ln1_b = (const float*)d_in[20];
    const float* res_w1 = (const float*)d_in[21];
    const float* res_b1 = (const float*)d_in[22];
    const float* res_ln_g = (const float*)d_in[23];
    const float* res_ln_b = (const float*)d_in[24];
    const float* res_w2 = (const float*)d_in[25];
    const float* res_b2 = (const float*)d_in[26];
    const float* op_ln2_g = (const float*)d_in[27];
    const float* op_ln2_b = (const float*)d_in[28];
    const float* op_w3 = (const float*)d_in[29];
    const float* op_b3 = (const float*)d_in[30];

    char* ws = (char*)d_ws;
    const size_t MB = 1u << 20;
    ushort* Qb = (ushort*)(ws);
    ushort* Kb = (ushort*)(ws + 1 * MB);
    ushort* VTb2 = (ushort*)(ws + 2 * MB);
    ushort* Opart = (ushort*)(ws + 3 * MB);
    float* lpart = (float*)(ws + 7 * MB);
    int* bidx = (int*)(ws + 7 * MB + (256u << 10));
    float* cmin = (float*)(ws + 7 * MB + (272u << 10));
    float* cmax = (float*)(ws + 7 * MB + (274u << 10));
    float* CF = (float*)(ws + 7 * MB + (276u << 10));
    ushort* Wqkv = (ushort*)(ws + 7 * MB + (340u << 10));
    ushort* Wao = (ushort*)(ws + 7 * MB + (436u << 10));
    ushort* Wop1 = (ushort*)(ws + 7 * MB + (468u << 10));
    ushort* Wr1 = (ushort*)(ws + 7 * MB + (540u << 10));
    ushort* Wr2 = (ushort*)(ws + 7 * MB + (572u << 10));

    k_setup<<<NB_PACK + NB_CELL + 1, 256, 0, stream>>>(
        num_atoms, cell, attn_in_w, attn_out_w, op_w1, res_w1, res_w2,
        ce_w1, ce_b1, ce_w2, ce_b2,
        bidx, cmin, cmax, Wqkv, Wao, Wop1, Wr1, Wr2, CF);
    k_qkv<<<256, 256, 0, stream>>>(elems, emb, ln_in_g, ln_in_b, Wqkv, attn_in_b,
                                   Qb, Kb, VTb2);
    k_attn<<<dim3(NATOMS / 64, NHEAD, SPLIT), 256, 0, stream>>>(Qb, Kb, VTb2, Opart, lpart);
    k_back<<<256, 256, 0, stream>>>(Opart, lpart, Wao, attn_out_b, CF, coord, bidx,
                                    ln_feat_g, ln_feat_b, Wop1, op_b1, op_ln1_g, op_ln1_b,
                                    Wr1, res_b1, res_ln_g, res_ln_b, Wr2, res_b2,
                                    op_ln2_g, op_ln2_b, op_w3, op_b3, cmin, cmax,
                                    (float*)d_out);
}

// Round 8
// 177.184 us; speedup vs baseline: 3.1110x; 1.0124x over previous
//
#include <hip/hip_runtime.h>
#include <hip/hip_bf16.h>
#include <math.h>
#include <stdint.h>

#define NATOMS 4096
#define HD     128
#define NHEAD  4
#define DHEAD  32
#define FDIM   259
#define BATCH  128
#define H3X    384
#define SPLIT  4

typedef __attribute__((ext_vector_type(8))) short short8;
typedef __attribute__((ext_vector_type(4))) float float4v;
typedef __attribute__((ext_vector_type(16))) float f32x16;

__device__ __forceinline__ ushort f2bf(float f) {
    uint32_t u = __float_as_uint(f);
    return (ushort)((u + 0x7fffu + ((u >> 16) & 1u)) >> 16);
}
__device__ __forceinline__ float b2f(ushort u) {
    return __uint_as_float(((uint32_t)u) << 16);
}
__device__ __forceinline__ f32x16 z16() {
    f32x16 v;
#pragma unroll
    for (int i = 0; i < 16; i++) v[i] = 0.f;
    return v;
}

// ---------------- setup: weight pack (coalesced reads) | cell MLP | prep ------
#define NB_PACK 528
#define NB_CELL 128
__global__ __launch_bounds__(256) void k_setup(
        const int* __restrict__ num_atoms, const float* __restrict__ cell,
        const float* __restrict__ qkvw, const float* __restrict__ aow,
        const float* __restrict__ op1w, const float* __restrict__ r1w,
        const float* __restrict__ r2w,
        const float* __restrict__ ce_w1, const float* __restrict__ ce_b1,
        const float* __restrict__ ce_w2, const float* __restrict__ ce_b2,
        int* __restrict__ bidx, float* __restrict__ cmin, float* __restrict__ cmax,
        ushort* __restrict__ Wqkv, ushort* __restrict__ Wao,
        ushort* __restrict__ Wop1, ushort* __restrict__ Wr1, ushort* __restrict__ Wr2,
        float* __restrict__ CF) {
    __shared__ float hs[HD];
    __shared__ int start[BATCH + 1];
    const int t = threadIdx.x;
    if (blockIdx.x < NB_PACK) {
        // source-linear: coalesced fp32 reads, scattered bf16 writes
        int idx = blockIdx.x * 256 + t;
        if (idx < 49152) {                       // qkvw [128][384]
            int k = idx / 384, n = idx - k * 384;
            Wqkv[n * 128 + k] = f2bf(qkvw[idx]);
        } else if (idx < 65536) {                // aow [128][128]
            int j = idx - 49152; int k = j >> 7, n = j & 127;
            Wao[n * 128 + k] = f2bf(aow[j]);
        } else if (idx < 98688) {                // op1w [259][128]
            int j = idx - 65536; int k = j >> 7, n = j & 127;
            Wop1[n * 288 + k] = f2bf(op1w[j]);
        } else if (idx < 102400) {               // zero-pad k in [259,288)
            int j = idx - 98688; int n = j & 127, k = 259 + (j >> 7);
            Wop1[n * 288 + k] = 0;
        } else if (idx < 118784) {               // r1w [128][128]
            int j = idx - 102400; int k = j >> 7, n = j & 127;
            Wr1[n * 128 + k] = f2bf(r1w[j]);
        } else {                                 // r2w [128][128]
            int j = idx - 118784; int k = j >> 7, n = j & 127;
            Wr2[n * 128 + k] = f2bf(r2w[j]);
        }
    } else if (blockIdx.x < NB_PACK + NB_CELL) {
        int r = blockIdx.x - NB_PACK;
        if (t < 128) {
            float c0 = cell[r * 3 + 0], c1 = cell[r * 3 + 1], c2 = cell[r * 3 + 2];
            float h = c0 * ce_w1[t] + c1 * ce_w1[HD + t] + c2 * ce_w1[2 * HD + t] + ce_b1[t];
            h = h / (1.f + __expf(-h));
            hs[t] = h;
        }
        __syncthreads();
        if (t < 128) {
            float acc = ce_b2[t];
#pragma unroll 8
            for (int k = 0; k < HD; k++) acc += hs[k] * ce_w2[k * HD + t];
            CF[r * HD + t] = acc;
        }
    } else {
        if (t == 0) {
            int pos = 0;
            for (int b = 0; b < BATCH; b++) { start[b] = pos; pos += num_atoms[b]; }
            start[BATCH] = pos;
        }
        __syncthreads();
        if (t < 128) {
            int s = min(start[t], NATOMS), e = min(start[t + 1], NATOMS);
            for (int j = s; j < e; j++) bidx[j] = t;
            if (t == 0) {
                int total = min(start[BATCH], NATOMS);
                for (int j = total; j < NATOMS; j++) bidx[j] = BATCH - 1;
            }
        }
        for (int rr = t; rr < BATCH * 3; rr += 256) {
            float a0 = cell[rr * 3 + 0], a1 = cell[rr * 3 + 1], a2 = cell[rr * 3 + 2];
            cmin[rr] = fminf(a0, fminf(a1, a2)) + 1e-6f;
            cmax[rr] = fmaxf(a0, fmaxf(a1, a2)) - 1e-6f;
        }
    }
}

// ---------------- QKV: fused embed+LN prologue, MFMA GEMM, packed outputs -----
__global__ __launch_bounds__(256) void k_qkv(const int* __restrict__ elems,
                                             const float* __restrict__ emb,
                                             const float* __restrict__ lg,
                                             const float* __restrict__ lb,
                                             const ushort* __restrict__ Wt,
                                             const float* __restrict__ bias,
                                             ushort* __restrict__ Qb, ushort* __restrict__ Kb,
                                             ushort* __restrict__ VTb2) {
    __shared__ alignas(16) ushort Af[4][64][8];
    __shared__ alignas(16) ushort vt[128][16];
    const int t = threadIdx.x, w = t >> 6, lane = t & 63, quad = lane >> 4, lq = lane & 15;
    const int rb = blockIdx.x * 16;
    {
        int row = t >> 4, seg = t & 15;
        int e = elems[rb + row];
        const float* ep = emb + (size_t)e * HD + seg * 8;
        float v[8]; float s = 0.f, ss = 0.f;
#pragma unroll
        for (int j = 0; j < 8; j++) { v[j] = ep[j]; s += v[j]; ss += v[j] * v[j]; }
#pragma unroll
        for (int m = 1; m < 16; m <<= 1) { s += __shfl_xor(s, m); ss += __shfl_xor(ss, m); }
        float mean = s * (1.f / HD);
        float inv = rsqrtf(ss * (1.f / HD) - mean * mean + 1e-5f);
        ushort o[8];
#pragma unroll
        for (int j = 0; j < 8; j++)
            o[j] = f2bf((v[j] - mean) * inv * lg[seg * 8 + j] + lb[seg * 8 + j]);
        *(uint4*)&Af[seg >> 2][(seg & 3) * 16 + row][0] = *(uint4*)o;
    }
    __syncthreads();
    float4v acc[6];
#pragma unroll
    for (int i = 0; i < 6; i++) acc[i] = (float4v){0.f, 0.f, 0.f, 0.f};
#pragma unroll
    for (int kt = 0; kt < 4; kt++) {
        short8 af = *(const short8*)&Af[kt][lane][0];
#pragma unroll
        for (int i = 0; i < 6; i++) {
            int nt = w * 6 + i;
            short8 wf = *(const short8*)(Wt + (size_t)(lq + 16 * nt) * HD + kt * 32 + quad * 8);
            acc[i] = __builtin_amdgcn_mfma_f32_16x16x32_bf16(af, wf, acc[i], 0, 0, 0);
        }
    }
#pragma unroll
    for (int i = 0; i < 6; i++) {
        int col = lq + 16 * (w * 6 + i);
        float bb = bias[col];
#pragma unroll
        for (int r = 0; r < 4; r++) {
            float c = acc[i][r] + bb;
            int rowin = quad * 4 + r;
            int row = rb + rowin;
            if (col < 128) {
                Qb[(size_t)(((col >> 5) * NATOMS) + row) * 32 + (col & 31)] = f2bf(c * 0.25503483f);
            } else if (col < 256) {
                int cc = col - 128;
                Kb[(size_t)(((cc >> 5) * NATOMS) + row) * 32 + (cc & 31)] = f2bf(c);
            } else {
                vt[col - 256][rowin] = f2bf(c);
            }
        }
    }
    __syncthreads();
    if (t < 128) {
        int hh = t >> 5, d = t & 31;
        uint4 a0 = *(const uint4*)&vt[t][0];
        uint4 a1 = *(const uint4*)&vt[t][8];
        ushort* dst = VTb2 + ((size_t)(hh * 64 + (rb >> 6)) * 32 + d) * 64 + (rb & 63);
        *(uint4*)(dst) = a0;
        *(uint4*)(dst + 8) = a1;
    }
}

// ---------------- attention: 32x32x16, S^T/O^T, split-K -----------------------
__global__ __launch_bounds__(256) void k_attn(const ushort* __restrict__ Qb,
                                              const ushort* __restrict__ Kb,
                                              const ushort* __restrict__ VTb2,
                                              ushort* __restrict__ Opart,
                                              float* __restrict__ lpart) {
    __shared__ alignas(16) ushort P_s[4][32 * 72];
    __shared__ alignas(16) float OL[2][32 * 36];
    __shared__ float LL[2][32];
    const int t = threadIdx.x, w = t >> 6, lane = t & 63;
    const int l31 = lane & 31, hi = lane >> 5;
    const int qt = w & 1, kh2 = w >> 1;
    const int h = blockIdx.y, sp = blockIdx.z;
    const int q0 = blockIdx.x * 64;
    const int qrow = q0 + qt * 32 + l31;

    short8 qf0 = *(const short8*)(Qb + (size_t)(h * NATOMS + qrow) * 32 + hi * 8);
    short8 qf1 = *(const short8*)(Qb + (size_t)(h * NATOMS + qrow) * 32 + 16 + hi * 8);
    f32x16 O = z16();
    float lp = 0.f;
    ushort* Pw = &P_s[w][0];
    const int kstart = sp * (NATOMS / SPLIT) + kh2 * 64;

    for (int ck = 0; ck < (NATOMS / SPLIT) / 128; ck++) {
        int kb = kstart + ck * 128;
        const ushort* vbase = VTb2 + ((size_t)(h * 64 + (kb >> 6)) * 32 + l31) * 64;
#pragma unroll
        for (int kt = 0; kt < 2; kt++) {
            int kk = kb + kt * 32;
            const ushort* kp = Kb + (size_t)(h * NATOMS + kk + l31) * 32 + hi * 8;
            short8 kf0 = *(const short8*)(kp);
            short8 kf1 = *(const short8*)(kp + 16);
            f32x16 S = z16();
            S = __builtin_amdgcn_mfma_f32_32x32x16_bf16(kf0, qf0, S, 0, 0, 0);
            S = __builtin_amdgcn_mfma_f32_32x32x16_bf16(kf1, qf1, S, 0, 0, 0);
#pragma unroll
            for (int c = 0; c < 4; c++) {
                float p0 = exp2f(S[4 * c + 0]);
                float p1 = exp2f(S[4 * c + 1]);
                float p2 = exp2f(S[4 * c + 2]);
                float p3 = exp2f(S[4 * c + 3]);
                lp += (p0 + p1) + (p2 + p3);
                uint32_t u0 = __float_as_uint(p0) + 0x8000u;
                uint32_t u1 = __float_as_uint(p1) + 0x8000u;
                uint32_t u2 = __float_as_uint(p2) + 0x8000u;
                uint32_t u3 = __float_as_uint(p3) + 0x8000u;
                uint2 u;
                u.x = __builtin_amdgcn_perm(u1, u0, 0x07060302u);
                u.y = __builtin_amdgcn_perm(u3, u2, 0x07060302u);
                *(uint2*)(&Pw[l31 * 72 + kt * 32 + c * 8 + hi * 4]) = u;
            }
#pragma unroll
            for (int wd = 0; wd < 2; wd++) {
                int koff = kt * 32 + wd * 16;
                short8 vf = *(const short8*)(vbase + koff + hi * 8);
                short8 pf = *(const short8*)(&Pw[l31 * 72 + koff + hi * 8]);
                O = __builtin_amdgcn_mfma_f32_32x32x16_bf16(vf, pf, O, 0, 0, 0);
            }
        }
    }
    lp += __shfl_xor(lp, 32);
    if (kh2 == 0) {
#pragma unroll
        for (int c = 0; c < 4; c++) {
            float4 f = {O[4 * c + 0], O[4 * c + 1], O[4 * c + 2], O[4 * c + 3]};
            *(float4*)(&OL[qt][l31 * 36 + c * 8 + hi * 4]) = f;
        }
        if (hi == 0) LL[qt][l31] = lp;
    }
    __syncthreads();
    if (kh2 == 1) {
        lp += LL[qt][l31];
#pragma unroll
        for (int c = 0; c < 4; c++) {
            float4 f = *(const float4*)(&OL[qt][l31 * 36 + c * 8 + hi * 4]);
            float o0 = O[4 * c + 0] + f.x, o1 = O[4 * c + 1] + f.y;
            float o2 = O[4 * c + 2] + f.z, o3 = O[4 * c + 3] + f.w;
            uint2 u;
            u.x = (uint32_t)f2bf(o0) | ((uint32_t)f2bf(o1) << 16);
            u.y = (uint32_t)f2bf(o2) | ((uint32_t)f2bf(o3) << 16);
            *(uint2*)(Opart + (size_t)(sp * NATOMS + qrow) * HD + h * 32 + c * 8 + hi * 4) = u;
        }
        if (hi == 0) lpart[sp * (NHEAD * NATOMS) + h * NATOMS + qrow] = lp;
    }
}

// ---------------- back: fused ao+comb+op1+r1+r2+LN+w3+clamp, 8 waves ----------
// grid 256: block = 16 rows; 8 waves, each owns ONE col-tile of 16 (2 waves/SIMD
// for latency hiding across the 7-barrier chain).
__global__ __launch_bounds__(512) void k_back(
        const ushort* __restrict__ Opart, const float* __restrict__ lpart,
        const ushort* __restrict__ Wao, const float* __restrict__ aob,
        const float* __restrict__ CF, const float* __restrict__ coord,
        const int* __restrict__ bidx,
        const float* __restrict__ fg, const float* __restrict__ fb,
        const ushort* __restrict__ Wop1, const float* __restrict__ op1b,
        const float* __restrict__ l1g, const float* __restrict__ l1b,
        const ushort* __restrict__ Wr1, const float* __restrict__ r1b,
        const float* __restrict__ rlg, const float* __restrict__ rlb,
        const ushort* __restrict__ Wr2, const float* __restrict__ r2b,
        const float* __restrict__ l2g, const float* __restrict__ l2b,
        const float* __restrict__ w3, const float* __restrict__ b3,
        const float* __restrict__ cmin, const float* __restrict__ cmax,
        float* __restrict__ out) {
    __shared__ alignas(16) ushort AF1[9][64][8];
    __shared__ alignas(16) ushort AF2[4][64][8];
    __shared__ alignas(16) ushort AF3[4][64][8];
    __shared__ float RED[8][16][4];
    __shared__ float REDC[16][2];
    __shared__ float COORDS[16][3];
    const int t = threadIdx.x, w = t >> 6, lane = t & 63, quad = lane >> 4, lq = lane & 15;
    const int rb = blockIdx.x * 16;
    const int col = lq + 16 * w;

    // ---- stage A: split-combine + attn-out GEMM ----
    const int arow = rb + lq;
    float4v a0 = {0.f, 0.f, 0.f, 0.f};
#pragma unroll
    for (int h = 0; h < 4; h++) {
        float l = 0.f;
#pragma unroll
        for (int s = 0; s < SPLIT; s++) l += lpart[s * (NHEAD * NATOMS) + h * NATOMS + arow];
        float inv = 1.f / l;
        float pv[8];
#pragma unroll
        for (int j = 0; j < 8; j++) pv[j] = 0.f;
#pragma unroll
        for (int s = 0; s < SPLIT; s++) {
            short8 ov = *(const short8*)(Opart + (size_t)(s * NATOMS + arow) * HD + h * 32 + quad * 8);
#pragma unroll
            for (int j = 0; j < 8; j++) pv[j] += b2f((ushort)ov[j]);
        }
        short8 af;
#pragma unroll
        for (int j = 0; j < 8; j++) af[j] = (short)f2bf(pv[j] * inv);
        short8 w0 = *(const short8*)(Wao + (size_t)col * HD + h * 32 + quad * 8);
        a0 = __builtin_amdgcn_mfma_f32_16x16x32_bf16(af, w0, a0, 0, 0, 0);
    }
    float x1[4];
#pragma unroll
    for (int r = 0; r < 4; r++) x1[r] = a0[r] + aob[col];

    // ---- stage B: comb LN(259) -> AF1 ----
    float cfv[4];
#pragma unroll
    for (int r = 0; r < 4; r++) cfv[r] = CF[bidx[rb + quad * 4 + r] * HD + col];
#pragma unroll
    for (int r = 0; r < 4; r++) {
        float s1 = x1[r] + cfv[r];
        float s2 = x1[r] * x1[r] + cfv[r] * cfv[r];
#pragma unroll
        for (int m = 1; m < 16; m <<= 1) { s1 += __shfl_xor(s1, m); s2 += __shfl_xor(s2, m); }
        if (lq == 0) { RED[w][quad * 4 + r][0] = s1; RED[w][quad * 4 + r][1] = s2; }
    }
    if (t < 16) {
        float c0 = coord[(rb + t) * 3 + 0], c1 = coord[(rb + t) * 3 + 1], c2 = coord[(rb + t) * 3 + 2];
        COORDS[t][0] = c0; COORDS[t][1] = c1; COORDS[t][2] = c2;
        REDC[t][0] = c0 + c1 + c2; REDC[t][1] = c0 * c0 + c1 * c1 + c2 * c2;
    }
    if (t < 64) { uint4 z = {0, 0, 0, 0}; *(uint4*)&AF1[8][t][0] = z; }
    __syncthreads();
#pragma unroll
    for (int r = 0; r < 4; r++) {
        int ri = quad * 4 + r;
        float s1 = REDC[ri][0], s2 = REDC[ri][1];
#pragma unroll
        for (int ww = 0; ww < 8; ww++) { s1 += RED[ww][ri][0]; s2 += RED[ww][ri][1]; }
        float mn = s1 * (1.f / FDIM);
        float iv = rsqrtf(s2 * (1.f / FDIM) - mn * mn + 1e-5f);
        float vx = (x1[r] - mn) * iv * fg[col] + fb[col];
        float vc = (cfv[r] - mn) * iv * fg[col + 128] + fb[col + 128];
        AF1[col >> 5][((col >> 3) & 3) * 16 + ri][col & 7] = f2bf(vx);
        int c2 = col + 128;
        AF1[c2 >> 5][((c2 >> 3) & 3) * 16 + ri][c2 & 7] = f2bf(vc);
    }
    if (t < 16) {
        float s1 = REDC[t][0], s2 = REDC[t][1];
#pragma unroll
        for (int ww = 0; ww < 8; ww++) { s1 += RED[ww][t][0]; s2 += RED[ww][t][1]; }
        float mn = s1 * (1.f / FDIM);
        float iv = rsqrtf(s2 * (1.f / FDIM) - mn * mn + 1e-5f);
#pragma unroll
        for (int c = 0; c < 3; c++)
            AF1[8][t][c] = f2bf((COORDS[t][c] - mn) * iv * fg[256 + c] + fb[256 + c]);
    }
    __syncthreads();

    // ---- stage C: op1 (K=288) + LN + silu -> AF2 ----
    float4v cv = {0.f, 0.f, 0.f, 0.f};
#pragma unroll
    for (int kt = 0; kt < 9; kt++) {
        short8 af = *(const short8*)&AF1[kt][lane][0];
        short8 w0 = *(const short8*)(Wop1 + (size_t)col * 288 + kt * 32 + quad * 8);
        cv = __builtin_amdgcn_mfma_f32_16x16x32_bf16(af, w0, cv, 0, 0, 0);
    }
    float h0[4];
#pragma unroll
    for (int r = 0; r < 4; r++) {
        h0[r] = cv[r] + op1b[col];
        float s1 = h0[r], s2 = h0[r] * h0[r];
#pragma unroll
        for (int m = 1; m < 16; m <<= 1) { s1 += __shfl_xor(s1, m); s2 += __shfl_xor(s2, m); }
        if (lq == 0) { RED[w][quad * 4 + r][0] = s1; RED[w][quad * 4 + r][1] = s2; }
    }
    __syncthreads();
#pragma unroll
    for (int r = 0; r < 4; r++) {
        int ri = quad * 4 + r;
        float s1 = 0.f, s2 = 0.f;
#pragma unroll
        for (int ww = 0; ww < 8; ww++) { s1 += RED[ww][ri][0]; s2 += RED[ww][ri][1]; }
        float mn = s1 * (1.f / HD);
        float iv = rsqrtf(s2 * (1.f / HD) - mn * mn + 1e-5f);
        float o = (h0[r] - mn) * iv * l1g[col] + l1b[col];
        o = o / (1.f + __expf(-o));
        AF2[col >> 5][((col >> 3) & 3) * 16 + ri][col & 7] = f2bf(o);
    }
    __syncthreads();

    // ---- stage D: r1 + LN + silu -> AF3 ----
    float4v dv = {0.f, 0.f, 0.f, 0.f};
#pragma unroll
    for (int kt = 0; kt < 4; kt++) {
        short8 af = *(const short8*)&AF2[kt][lane][0];
        short8 w0 = *(const short8*)(Wr1 + (size_t)col * HD + kt * 32 + quad * 8);
        dv = __builtin_amdgcn_mfma_f32_16x16x32_bf16(af, w0, dv, 0, 0, 0);
    }
    float e0[4];
#pragma unroll
    for (int r = 0; r < 4; r++) {
        e0[r] = dv[r] + r1b[col];
        float s1 = e0[r], s2 = e0[r] * e0[r];
#pragma unroll
        for (int m = 1; m < 16; m <<= 1) { s1 += __shfl_xor(s1, m); s2 += __shfl_xor(s2, m); }
        if (lq == 0) { RED[w][quad * 4 + r][0] = s1; RED[w][quad * 4 + r][1] = s2; }
    }
    __syncthreads();
#pragma unroll
    for (int r = 0; r < 4; r++) {
        int ri = quad * 4 + r;
        float s1 = 0.f, s2 = 0.f;
#pragma unroll
        for (int ww = 0; ww < 8; ww++) { s1 += RED[ww][ri][0]; s2 += RED[ww][ri][1]; }
        float mn = s1 * (1.f / HD);
        float iv = rsqrtf(s2 * (1.f / HD) - mn * mn + 1e-5f);
        float o = (e0[r] - mn) * iv * rlg[col] + rlb[col];
        o = o / (1.f + __expf(-o));
        AF3[col >> 5][((col >> 3) & 3) * 16 + ri][col & 7] = f2bf(o);
    }
    __syncthreads();

    // ---- stage E: r2 + resid + LN + w3 + tanh + clamp ----
    float4v fv = {0.f, 0.f, 0.f, 0.f};
#pragma unroll
    for (int kt = 0; kt < 4; kt++) {
        short8 af = *(const short8*)&AF3[kt][lane][0];
        short8 w0 = *(const short8*)(Wr2 + (size_t)col * HD + kt * 32 + quad * 8);
        fv = __builtin_amdgcn_mfma_f32_16x16x32_bf16(af, w0, fv, 0, 0, 0);
    }
    float g0r[4];
#pragma unroll
    for (int r = 0; r < 4; r++) {
        int ri = quad * 4 + r;
        float rs = b2f(AF2[col >> 5][((col >> 3) & 3) * 16 + ri][col & 7]);
        g0r[r] = fv[r] + r2b[col] + rs;
        float s1 = g0r[r], s2 = g0r[r] * g0r[r];
#pragma unroll
        for (int m = 1; m < 16; m <<= 1) { s1 += __shfl_xor(s1, m); s2 += __shfl_xor(s2, m); }
        if (lq == 0) { RED[w][ri][0] = s1; RED[w][ri][1] = s2; }
    }
    __syncthreads();
    float tp[4][3];
#pragma unroll
    for (int r = 0; r < 4; r++) {
        int ri = quad * 4 + r;
        float s1 = 0.f, s2 = 0.f;
#pragma unroll
        for (int ww = 0; ww < 8; ww++) { s1 += RED[ww][ri][0]; s2 += RED[ww][ri][1]; }
        float mn = s1 * (1.f / HD);
        float iv = rsqrtf(s2 * (1.f / HD) - mn * mn + 1e-5f);
        float h2 = (g0r[r] - mn) * iv * l2g[col] + l2b[col];
#pragma unroll
        for (int c = 0; c < 3; c++) {
            float v = h2 * w3[col * 3 + c];
#pragma unroll
            for (int m = 1; m < 16; m <<= 1) v += __shfl_xor(v, m);
            tp[r][c] = v;
        }
    }
    __syncthreads();
    if (lq == 0) {
#pragma unroll
        for (int r = 0; r < 4; r++) {
            RED[w][quad * 4 + r][0] = tp[r][0];
            RED[w][quad * 4 + r][1] = tp[r][1];
            RED[w][quad * 4 + r][2] = tp[r][2];
        }
    }
    __syncthreads();
    if (t < 16) {
        int bi = bidx[rb + t];
#pragma unroll
        for (int c = 0; c < 3; c++) {
            float sv = 0.f;
#pragma unroll
            for (int ww = 0; ww < 8; ww++) sv += RED[ww][t][c];
            float off = tanhf(sv + b3[c]) * 0.01f;
            float pert = COORDS[t][c] + off;
            pert = fminf(fmaxf(pert, cmin[bi * 3 + c]), cmax[bi * 3 + c]);
            out[(rb + t) * 3 + c] = pert;
        }
    }
}

extern "C" void kernel_launch(void* const* d_in, const int* in_sizes, int n_in,
                              void* d_out, int out_size, void* d_ws, size_t ws_size,
                              hipStream_t stream) {
    const int* num_atoms = (const int*)d_in[0];
    const int* elems = (const int*)d_in[1];
    const float* cell = (const float*)d_in[2];
    const float* coord = (const float*)d_in[3];
    const float* emb = (const float*)d_in[4];
    const float* ln_in_g = (const float*)d_in[5];
    const float* ln_in_b = (const float*)d_in[6];
    const float* attn_in_w = (const float*)d_in[7];
    const float* attn_in_b = (const float*)d_in[8];
    const float* attn_out_w = (const float*)d_in[9];
    const float* attn_out_b = (const float*)d_in[10];
    const float* ce_w1 = (const float*)d_in[11];
    const float* ce_b1 = (const float*)d_in[12];
    const float* ce_w2 = (const float*)d_in[13];
    const float* ce_b2 = (const float*)d_in[14];
    const float* ln_feat_g = (const float*)d_in[15];
    const float* ln_feat_b = (const float*)d_in[16];
    const float* op_w1 = (const float*)d_in[17];
    const float* op_b1 = (const float*)d_in[18];
    const float* op_ln1_g = (const float*)d_in[19];
    const float* op_ln1_b = (const float*)d_in[20];
    const float* res_w1 = (const float*)d_in[21];
    const float* res_b1 = (const float*)d_in[22];
    const float* res_ln_g = (const float*)d_in[23];
    const float* res_ln_b = (const float*)d_in[24];
    const float* res_w2 = (const float*)d_in[25];
    const float* res_b2 = (const float*)d_in[26];
    const float* op_ln2_g = (const float*)d_in[27];
    const float* op_ln2_b = (const float*)d_in[28];
    const float* op_w3 = (const float*)d_in[29];
    const float* op_b3 = (const float*)d_in[30];

    char* ws = (char*)d_ws;
    const size_t MB = 1u << 20;
    ushort* Qb = (ushort*)(ws);
    ushort* Kb = (ushort*)(ws + 1 * MB);
    ushort* VTb2 = (ushort*)(ws + 2 * MB);
    ushort* Opart = (ushort*)(ws + 3 * MB);
    float* lpart = (float*)(ws + 7 * MB);
    int* bidx = (int*)(ws + 7 * MB + (256u << 10));
    float* cmin = (float*)(ws + 7 * MB + (272u << 10));
    float* cmax = (float*)(ws + 7 * MB + (274u << 10));
    float* CF = (float*)(ws + 7 * MB + (276u << 10));
    ushort* Wqkv = (ushort*)(ws + 7 * MB + (340u << 10));
    ushort* Wao = (ushort*)(ws + 7 * MB + (436u << 10));
    ushort* Wop1 = (ushort*)(ws + 7 * MB + (468u << 10));
    ushort* Wr1 = (ushort*)(ws + 7 * MB + (540u << 10));
    ushort* Wr2 = (ushort*)(ws + 7 * MB + (572u << 10));

    k_setup<<<NB_PACK + NB_CELL + 1, 256, 0, stream>>>(
        num_atoms, cell, attn_in_w, attn_out_w, op_w1, res_w1, res_w2,
        ce_w1, ce_b1, ce_w2, ce_b2,
        bidx, cmin, cmax, Wqkv, Wao, Wop1, Wr1, Wr2, CF);
    k_qkv<<<256, 256, 0, stream>>>(elems, emb, ln_in_g, ln_in_b, Wqkv, attn_in_b,
                                   Qb, Kb, VTb2);
    k_attn<<<dim3(NATOMS / 64, NHEAD, SPLIT), 256, 0, stream>>>(Qb, Kb, VTb2, Opart, lpart);
    k_back<<<256, 512, 0, stream>>>(Opart, lpart, Wao, attn_out_b, CF, coord, bidx,
                                    ln_feat_g, ln_feat_b, Wop1, op_b1, op_ln1_g, op_ln1_b,
                                    Wr1, res_b1, res_ln_g, res_ln_b, Wr2, res_b2,
                                    op_ln2_g, op_ln2_b, op_w3, op_b3, cmin, cmax,
                                    (float*)d_out);
}